// Round 3
// baseline (265.768 us; speedup 1.0000x reference)
//
#include <hip/hip_runtime.h>
#include <stdint.h>

// NNCLR forward on MI355X — round 8.
// Changes vs round 7b:
//  * k2_mfma restructured: round-7b doubled occupancy but dur stayed 98 us (MfmaUtil/
//    VALU/HBM all ~14%) -> per-wave critical path bound by scattered global pf loads
//    from Phi inside the ks loop (512 MB aggregate L2 traffic for a 0.5 MB operand).
//    New decomposition: 4 m-strips x 256 queue-chunks; each wave holds its 64 m-rows
//    x K=256 of Phi RESIDENT in 128 VGPRs (loaded once per block). Inner loop is
//    ds_read+MFMA only. Queue tiles (64 rows) double-buffered in LDS (2x32KB, same
//    zero-conflict swizzle). VGPR ~230 -> 2 waves/SIMD -> 2 blocks/CU co-resident,
//    cross-block overlap covers the stage phase.
//  * k1 / k2b / k2c / k2d / k3 / k4 unchanged (passed, absmax 0).

#define BATCH  512
#define DIM    256
#define QUEUE  65536
#define MROWS  1024
#define NGRP   2048          // 65536 / 32
#define MARGIN 0.01f

typedef short bf16x8 __attribute__((ext_vector_type(8)));
typedef float f32x4  __attribute__((ext_vector_type(4)));

__device__ __forceinline__ unsigned int mono_f32(float f) {
    unsigned int u = __float_as_uint(f);
    return (u & 0x80000000u) ? ~u : (u | 0x80000000u);
}
__device__ __forceinline__ float unmono_f32(unsigned int m) {
    unsigned int u = (m & 0x80000000u) ? (m ^ 0x80000000u) : ~m;
    return __uint_as_float(u);
}
__device__ __forceinline__ unsigned short f2bf(float f) {   // RNE fp32->bf16
    unsigned int u = __float_as_uint(f);
    return (unsigned short)((u + 0x7fffu + ((u >> 16) & 1u)) >> 16);
}

// ---------------- k1: normalize + ws init ----------------
__global__ void k1_norm(const float* __restrict__ p1, const float* __restrict__ p2,
                        float* __restrict__ Pn, float* __restrict__ PnT,
                        unsigned short* __restrict__ Phi, float* __restrict__ outq,
                        int* __restrict__ npairs, unsigned int* __restrict__ rowmaxU,
                        unsigned long long* __restrict__ rowfinal)
{
    const int r = blockIdx.x;        // 0..1023
    const int t = threadIdx.x;       // 0..63
    if (t == 0) {                    // stream-ordered init (ws poisoned 0xAA each call)
        rowmaxU[r] = 0u;
        rowfinal[r] = 0ull;
        if (r == 0) *npairs = 0;
    }
    const float* src = (r < BATCH) ? p1 : p2;
    const int row = (r < BATCH) ? r : r - BATCH;
    float4 v = ((const float4*)(src + (size_t)row * DIM))[t];
    float sq = v.x*v.x + v.y*v.y + v.z*v.z + v.w*v.w;
    #pragma unroll
    for (int off = 32; off; off >>= 1) sq += __shfl_xor(sq, off, 64);
    sq = fmaxf(sq, 1e-12f);
    float s = rsqrtf(sq);
    s = s * (1.5f - 0.5f * sq * s * s);
    v.x *= s; v.y *= s; v.z *= s; v.w *= s;
    ((float4*)(Pn + (size_t)r * DIM))[t] = v;
    const int k = t * 4;
    PnT[(size_t)(k + 0) * MROWS + r] = v.x;
    PnT[(size_t)(k + 1) * MROWS + r] = v.y;
    PnT[(size_t)(k + 2) * MROWS + r] = v.z;
    PnT[(size_t)(k + 3) * MROWS + r] = v.w;
    short4 b;
    b.x = (short)f2bf(v.x); b.y = (short)f2bf(v.y);
    b.z = (short)f2bf(v.z); b.w = (short)f2bf(v.w);
    ((short4*)Phi)[(size_t)r * (DIM / 4) + t] = b;
    if (r < BATCH) ((float4*)(outq + (size_t)r * DIM))[t] = v;  // new_queue[0:512] = p1n
}

// ---------------- k2: P-resident-in-registers MFMA filter + fused convert + FIFO copy ------
// Grid 1024 = 4 m-strips x 256 queue-chunks (256 rows each). Block = 256 thr = 4 waves;
// wave w owns m-rows [s*256 + w*64, +64), K=256 Phi fragment resident in 128 VGPRs.
// Queue tiles of 64 rows double-buffered in LDS (2x32KB), swizzle: 16B chunk (r,c16) at
// r*512 + ((c16 ^ (r&31)) << 4). mfma(Qfrag, Pfrag): C rows = n (q*4+reg), C cols = m (lr).
// Only strip 0 does the FIFO copy to outq.
__device__ __forceinline__ void k2_stage(const float* __restrict__ queue,
                                         float* __restrict__ outq,
                                         char* Bsb, int nr, int tid, bool docopy)
{
    const f32x4* qsrc = (const f32x4*)(queue + (size_t)nr * DIM);
    f32x4* qdst = (f32x4*)(outq + (size_t)(nr + BATCH) * DIM);
    #pragma unroll 4
    for (int it = 0; it < 16; ++it) {
        const int L = it * 256 + tid;        // 0..4095
        const int r = L >> 6, h = L & 63;
        f32x4 v = qsrc[(size_t)r * 64 + h];
        if (docopy && (nr + r < QUEUE - BATCH))
            __builtin_nontemporal_store(v, qdst + (size_t)r * 64 + h);
        short4 b;
        b.x = (short)f2bf(v.x); b.y = (short)f2bf(v.y);
        b.z = (short)f2bf(v.z); b.w = (short)f2bf(v.w);
        const int c16 = h >> 1, hf = h & 1;
        *(short4*)(Bsb + r * 512 + ((c16 ^ (r & 31)) << 4) + hf * 8) = b;
    }
}

__global__ __launch_bounds__(256, 2)
void k2_mfma(const unsigned short* __restrict__ Phi, const float* __restrict__ queue,
             float* __restrict__ outq, float* __restrict__ cand)
{
    __shared__ __align__(16) char Bs[2][32768];
    const int bid = blockIdx.x;      // 0..1023
    const int s = bid >> 8;          // m-strip 0..3
    const int c = bid & 255;         // queue chunk 0..255
    const int t  = threadIdx.x;
    const int w  = t >> 6, lane = t & 63;
    const int lr = lane & 15, q = lane >> 4;
    const int mbase = s * 256 + w * 64;
    const int n0 = c * 256;
    const bool docopy = (s == 0);

    // ---- preload P fragments: 64 m-rows x K=256, resident (32 x bf16x8 = 128 VGPR)
    bf16x8 pfr[4][8];
    {
        const unsigned short* Pw = Phi + (size_t)(mbase + lr) * DIM + q * 8;
        #pragma unroll
        for (int mj = 0; mj < 4; ++mj)
            #pragma unroll
            for (int ks = 0; ks < 8; ++ks)
                pfr[mj][ks] = *(const bf16x8*)(Pw + (size_t)mj * 16 * DIM + ks * 32);
    }

    k2_stage(queue, outq, Bs[0], n0, t, docopy);
    __syncthreads();

    for (int tl = 0; tl < 4; ++tl) {
        char* Bsb = Bs[tl & 1];
        f32x4 acc[4][4];                 // [ni][mj]
        #pragma unroll
        for (int i = 0; i < 4; ++i)
            #pragma unroll
            for (int j = 0; j < 4; ++j) acc[i][j] = (f32x4){0.f, 0.f, 0.f, 0.f};

        #pragma unroll
        for (int ks = 0; ks < 8; ++ks) {
            bf16x8 qf[4];
            #pragma unroll
            for (int ni = 0; ni < 4; ++ni) {
                const int r = ni * 16 + lr;
                const int c16 = ks * 4 + q;
                qf[ni] = *(const bf16x8*)(Bsb + r * 512 + ((c16 ^ (r & 31)) << 4));
            }
            #pragma unroll
            for (int ni = 0; ni < 4; ++ni)
                #pragma unroll
                for (int mj = 0; mj < 4; ++mj)
                    acc[ni][mj] = __builtin_amdgcn_mfma_f32_16x16x32_bf16(qf[ni], pfr[mj][ks], acc[ni][mj], 0, 0, 0);
        }

        // ---- epilogue: per (m, 32-n-group) max. n in-lane (+q), m across 16 lanes.
        #pragma unroll
        for (int mj = 0; mj < 4; ++mj) {
            #pragma unroll
            for (int gl = 0; gl < 2; ++gl) {
                f32x4 va = acc[2 * gl][mj], vb = acc[2 * gl + 1][mj];
                float mx = fmaxf(fmaxf(fmaxf(va[0], va[1]), fmaxf(va[2], va[3])),
                                 fmaxf(fmaxf(vb[0], vb[1]), fmaxf(vb[2], vb[3])));
                mx = fmaxf(mx, __shfl_xor(mx, 16, 64));
                mx = fmaxf(mx, __shfl_xor(mx, 32, 64));
                if (q == 0)
                    cand[(size_t)(c * 8 + tl * 2 + gl) * MROWS + (mbase + mj * 16 + lr)] = mx;
            }
        }

        if (tl < 3)
            k2_stage(queue, outq, Bs[(tl + 1) & 1], n0 + (tl + 1) * 64, t, docopy);
        __syncthreads();
    }
}

// ---------------- k2b: per-row max over groups (wide, pipelined) ----------------
// grid = 16 m-chunks x 16 g-chunks = 256 blocks; wave gs scans 32 g's, unrolled.
__global__ void k2b_rowmax(const float* __restrict__ cand, unsigned int* __restrict__ rowmaxU)
{
    const int t  = threadIdx.x;              // 256
    const int ml = t & 63, gs = t >> 6;
    const int mc = blockIdx.x & 15, gc = blockIdx.x >> 4;
    const int m  = mc * 64 + ml;
    const int g0 = gc * 128 + gs * 32;
    float mx = -1e30f;
    #pragma unroll 8
    for (int j = 0; j < 32; ++j)
        mx = fmaxf(mx, cand[(size_t)(g0 + j) * MROWS + m]);
    __shared__ float pm[4][64];
    pm[gs][ml] = mx;
    __syncthreads();
    if (gs == 0) {
        mx = fmaxf(fmaxf(pm[0][ml], pm[1][ml]), fmaxf(pm[2][ml], pm[3][ml]));
        atomicMax(rowmaxU + m, mono_f32(mx));
    }
}

// ---------------- k2c: margin filter -> pair list (wide, pipelined) ----------------
__global__ void k2c_filter(const float* __restrict__ cand, const unsigned int* __restrict__ rowmaxU,
                           unsigned int* __restrict__ pairs, int* __restrict__ npairs)
{
    const int t  = threadIdx.x;              // 256
    const int ml = t & 63, gs = t >> 6;
    const int mc = blockIdx.x & 15, gc = blockIdx.x >> 4;
    const int m  = mc * 64 + ml;
    const int g0 = gc * 128 + gs * 32;
    const float thr = unmono_f32(rowmaxU[m]) - MARGIN;
    #pragma unroll 8
    for (int j = 0; j < 32; ++j) {
        if (cand[(size_t)(g0 + j) * MROWS + m] >= thr) {
            int p = atomicAdd(npairs, 1);
            pairs[p] = ((unsigned int)m << 16) | (unsigned int)(g0 + j);
        }
    }
}

// ---------------- k2d: exact fp32 rescore, one wave per (row,group) ----------------
__global__ __launch_bounds__(256, 4)
void k2d_rescore(const unsigned int* __restrict__ pairs, const int* __restrict__ npairs,
                 const float* __restrict__ Pn, const float* __restrict__ queue,
                 unsigned long long* __restrict__ rowfinal)
{
    const int t = threadIdx.x, w = t >> 6, lane = t & 63;
    const int n = *npairs;
    const int col_l = lane & 31, half = lane >> 5;
    for (int p = blockIdx.x * 4 + w; p < n; p += gridDim.x * 4) {
        const unsigned int pr = pairs[p];
        const int row = pr >> 16, g = pr & 0xffff;
        const int col = g * 32 + col_l;
        const float4* qp = (const float4*)(queue + (size_t)col * DIM + half * 128);
        const float4* pp = (const float4*)(Pn + (size_t)row * DIM + half * 128);
        float4 sv = {0.f, 0.f, 0.f, 0.f};
        #pragma unroll 8
        for (int j = 0; j < 32; ++j) {
            float4 a = pp[j], b = qp[j];
            sv.x = fmaf(a.x, b.x, sv.x); sv.y = fmaf(a.y, b.y, sv.y);
            sv.z = fmaf(a.z, b.z, sv.z); sv.w = fmaf(a.w, b.w, sv.w);
        }
        float s = (sv.x + sv.y) + (sv.z + sv.w);
        s += __shfl_xor(s, 32, 64);                       // combine k-halves
        unsigned long long best = ((unsigned long long)mono_f32(s) << 32)
                                | (unsigned int)(65535 - col);
        #pragma unroll
        for (int off = 1; off <= 16; off <<= 1) {
            unsigned long long o = __shfl_xor(best, off, 64);
            best = best > o ? best : o;
        }
        if (lane == 0) atomicMax(rowfinal + row, best);
    }
}

// ---------------- k3: S1/S2 similarity matrices (8 rows x 256-col half per block) --------
// grid 256: b>>1 = row-block (8 rows of [nn1;nn2]), b&1 = column half.
__global__ void k3_sim(const unsigned long long* __restrict__ rowfinal,
                       const float* __restrict__ queue,
                       const float* __restrict__ PnT, float* __restrict__ S)
{
    const int b  = blockIdx.x;       // 0..255
    const int rb = (b >> 1) * 8;     // 0..1016 (rows of [nn1;nn2])
    const int ch = b & 1;            // column half
    const int tid = threadIdx.x;     // 256
    const int which = (rb < BATCH) ? 0 : 1;
    const int colbase = which ? 0 : BATCH;    // S1 vs p2 (cols 512..1023), S2 vs p1 (0..511)
    const int col = colbase + ch * 256 + tid;
    __shared__ float nnv[8][DIM];
    #pragma unroll
    for (int j = 0; j < 8; ++j) {
        const int idx = 65535 - (int)(rowfinal[rb + j] & 0xFFFFull);
        nnv[j][tid] = queue[(size_t)idx * DIM + tid];
    }
    __syncthreads();
    float acc[8];
    #pragma unroll
    for (int j = 0; j < 8; ++j) acc[j] = 0.f;
    for (int k4 = 0; k4 < 64; ++k4) {
        float4 nv[8];
        #pragma unroll
        for (int j = 0; j < 8; ++j) nv[j] = ((const float4*)nnv[j])[k4];
        #pragma unroll
        for (int kk = 0; kk < 4; ++kk) {
            const int k = k4 * 4 + kk;
            const float v0 = PnT[(size_t)k * MROWS + col];
            #pragma unroll
            for (int j = 0; j < 8; ++j) {
                const float nj = ((const float*)&nv[j])[kk];
                acc[j] = fmaf(nj, v0, acc[j]);
            }
        }
    }
    const int i0 = rb & (BATCH - 1);
    float* Sout = S + (size_t)which * (BATCH * BATCH);
    #pragma unroll
    for (int j = 0; j < 8; ++j)
        Sout[(size_t)(i0 + j) * BATCH + ch * 256 + tid] = acc[j] * 10.0f;
}

// ---------------- k4: loss ----------------
__global__ void k4_loss(const float* __restrict__ S, float* __restrict__ loss)
{
    const int r = blockIdx.x;        // 0..2047
    const int tid = threadIdx.x;     // 256
    const int grp = r >> 9;
    const int i = r & 511;
    const float* M = S + (size_t)(grp >> 1) * (BATCH * BATCH);
    float x0, x1;
    if (!(grp & 1)) { x0 = M[(size_t)i * BATCH + tid];  x1 = M[(size_t)i * BATCH + tid + 256]; }
    else            { x0 = M[(size_t)tid * BATCH + i];  x1 = M[(size_t)(tid + 256) * BATCH + i]; }
    const float diag = M[(size_t)i * BATCH + i];
    float mx = fmaxf(x0, x1);
    #pragma unroll
    for (int off = 1; off < 64; off <<= 1) mx = fmaxf(mx, __shfl_xor(mx, off, 64));
    __shared__ float redm[4], reds[4];
    if ((tid & 63) == 0) redm[tid >> 6] = mx;
    __syncthreads();
    mx = fmaxf(fmaxf(redm[0], redm[1]), fmaxf(redm[2], redm[3]));
    float e = __expf(x0 - mx) + __expf(x1 - mx);
    #pragma unroll
    for (int off = 1; off < 64; off <<= 1) e += __shfl_xor(e, off, 64);
    if ((tid & 63) == 0) reds[tid >> 6] = e;
    __syncthreads();
    if (tid == 0)
        loss[r] = mx + logf(reds[0] + reds[1] + reds[2] + reds[3]) - diag;
}

// ---------------- launcher ----------------
extern "C" void kernel_launch(void* const* d_in, const int* in_sizes, int n_in,
                              void* d_out, int out_size, void* d_ws, size_t ws_size,
                              hipStream_t stream)
{
    const float* p1    = (const float*)d_in[0];
    const float* p2    = (const float*)d_in[1];
    const float* queue = (const float*)d_in[2];
    float* out  = (float*)d_out;
    float* loss = out;
    float* outq = out + 4 * BATCH;

    // Workspace (~20.6 MB)
    char* w = (char*)d_ws;
    float* cand = (float*)w;                               w += (size_t)NGRP * MROWS * 4;   // 8 MB [g][m]
    unsigned long long* rowfinal = (unsigned long long*)w; w += MROWS * 8;
    unsigned int* rowmaxU = (unsigned int*)w;              w += MROWS * 4;
    float* Pn  = (float*)w;                                w += (size_t)MROWS * DIM * 4;    // 1 MB
    float* PnT = (float*)w;                                w += (size_t)MROWS * DIM * 4;    // 1 MB
    unsigned short* Phi = (unsigned short*)w;              w += (size_t)MROWS * DIM * 2;    // 0.5 MB
    float* S = (float*)w;                                  w += (size_t)2 * BATCH * BATCH * 4; // 2 MB
    unsigned int* pairs = (unsigned int*)w;                w += (size_t)NGRP * MROWS * 4;   // 8 MB (worst case)
    int* npairs = (int*)w;

    hipLaunchKernelGGL(k1_norm,     dim3(MROWS), dim3(64),  0, stream, p1, p2, Pn, PnT, Phi, outq,
                       npairs, rowmaxU, rowfinal);
    hipLaunchKernelGGL(k2_mfma,     dim3(1024), dim3(256), 0, stream, Phi, queue, outq, cand);
    hipLaunchKernelGGL(k2b_rowmax,  dim3(256),   dim3(256), 0, stream, cand, rowmaxU);
    hipLaunchKernelGGL(k2c_filter,  dim3(256),   dim3(256), 0, stream, cand, rowmaxU, pairs, npairs);
    hipLaunchKernelGGL(k2d_rescore, dim3(512),   dim3(256), 0, stream, pairs, npairs, Pn, queue, rowfinal);
    hipLaunchKernelGGL(k3_sim,      dim3(256),   dim3(256), 0, stream, rowfinal, queue, PnT, S);
    hipLaunchKernelGGL(k4_loss,     dim3(4 * BATCH), dim3(256), 0, stream, S, loss);
}

// Round 4
// 245.612 us; speedup vs baseline: 1.0821x; 1.0821x over previous
//
#include <hip/hip_runtime.h>
#include <stdint.h>

// NNCLR forward on MI355X — round 9.
// Changes vs round 8:
//  * Diagnosis: rounds 6/7b/8 all ~100 us. Round 8's VGPR_Count=128 (need ~230) + FETCH
//    35->85 MB => pfr spilled to scratch; inner loop still had global traffic. Root cause:
//    fp32->bf16 conversion staging forces a fat VALU loop + register pressure.
//  * k0_prep (new): streaming pass. queue -> outq FIFO copy (nt) + Qbf: bf16 image of
//    queue PRE-SWIZZLED as the exact 64-row LDS tile image. ~160 MB, HBM-bound.
//  * k1: Phi now written in fragment-ready layout (PhiF) -> k2 preload is coalesced.
//  * k2_mfma: pure bf16 GEMM, round-8 geometry (4 strips x 256 chunks, wave = 64m x 64n,
//    pfr[4][8] resident), staging via global_load_lds(16B) from Qbf (zero VALU, zero data
//    regs -> no spill pressure), dbuf, 1 barrier/tile. Inner: 4 ds_read + 16 MFMA per ks.
//  * Qbf (32 MB) aliases pairs (liveness disjoint: Qbf dead after k2, pairs born in k2c).
//  * k2b / k2c / k2d / k3 / k4 unchanged (passed, absmax 0).

#define BATCH  512
#define DIM    256
#define QUEUE  65536
#define MROWS  1024
#define NGRP   2048          // 65536 / 32
#define MARGIN 0.01f

typedef short bf16x8 __attribute__((ext_vector_type(8)));
typedef float f32x4  __attribute__((ext_vector_type(4)));

__device__ __forceinline__ unsigned int mono_f32(float f) {
    unsigned int u = __float_as_uint(f);
    return (u & 0x80000000u) ? ~u : (u | 0x80000000u);
}
__device__ __forceinline__ float unmono_f32(unsigned int m) {
    unsigned int u = (m & 0x80000000u) ? (m ^ 0x80000000u) : ~m;
    return __uint_as_float(u);
}
__device__ __forceinline__ unsigned short f2bf(float f) {   // RNE fp32->bf16
    unsigned int u = __float_as_uint(f);
    return (unsigned short)((u + 0x7fffu + ((u >> 16) & 1u)) >> 16);
}

// ---------------- k1: normalize + PhiF (fragment layout) + ws init ----------------
// PhiF 16B-chunk index for (row r, k-chunk c = k/8): ((r>>4)*8 + (c>>2))*64 + (c&3)*16 + (r&15)
// so a wave's pfr load (lane = q*16+lr) is one coalesced 1KB b128 read per (mt16, ks).
__global__ void k1_norm(const float* __restrict__ p1, const float* __restrict__ p2,
                        float* __restrict__ Pn, float* __restrict__ PnT,
                        unsigned short* __restrict__ PhiF, float* __restrict__ outq,
                        int* __restrict__ npairs, unsigned int* __restrict__ rowmaxU,
                        unsigned long long* __restrict__ rowfinal)
{
    const int r = blockIdx.x;        // 0..1023
    const int t = threadIdx.x;       // 0..63
    if (t == 0) {                    // stream-ordered init (ws poisoned 0xAA each call)
        rowmaxU[r] = 0u;
        rowfinal[r] = 0ull;
        if (r == 0) *npairs = 0;
    }
    const float* src = (r < BATCH) ? p1 : p2;
    const int row = (r < BATCH) ? r : r - BATCH;
    float4 v = ((const float4*)(src + (size_t)row * DIM))[t];
    float sq = v.x*v.x + v.y*v.y + v.z*v.z + v.w*v.w;
    #pragma unroll
    for (int off = 32; off; off >>= 1) sq += __shfl_xor(sq, off, 64);
    sq = fmaxf(sq, 1e-12f);
    float s = rsqrtf(sq);
    s = s * (1.5f - 0.5f * sq * s * s);
    v.x *= s; v.y *= s; v.z *= s; v.w *= s;
    ((float4*)(Pn + (size_t)r * DIM))[t] = v;
    const int k = t * 4;
    PnT[(size_t)(k + 0) * MROWS + r] = v.x;
    PnT[(size_t)(k + 1) * MROWS + r] = v.y;
    PnT[(size_t)(k + 2) * MROWS + r] = v.z;
    PnT[(size_t)(k + 3) * MROWS + r] = v.w;
    short4 b;
    b.x = (short)f2bf(v.x); b.y = (short)f2bf(v.y);
    b.z = (short)f2bf(v.z); b.w = (short)f2bf(v.w);
    // fragment-ready: chunk c = t>>1 (8 bf16), this thread holds half (t&1)
    {
        const int c = t >> 1;
        const int idx = ((r >> 4) * 8 + (c >> 2)) * 64 + (c & 3) * 16 + (r & 15);
        *(short4*)((char*)PhiF + (size_t)idx * 16 + (t & 1) * 8) = b;
    }
    if (r < BATCH) ((float4*)(outq + (size_t)r * DIM))[t] = v;  // new_queue[0:512] = p1n
}

// ---------------- k0: queue -> outq FIFO copy + Qbf (pre-swizzled bf16 tile image) -----
// 1024 blocks, one per 64-row queue tile. Qbf tile b at byte b*32768; 16B chunk (r, c16)
// at r*512 + ((c16 ^ (r & 31)) << 4)  — identical to the LDS image k2 reads.
__global__ void k0_prep(const float* __restrict__ queue, float* __restrict__ outq,
                        char* __restrict__ Qbf)
{
    const int b = blockIdx.x;        // 0..1023
    const int t = threadIdx.x;       // 0..255
    const int n0 = b * 64;
    const f32x4* qsrc = (const f32x4*)(queue + (size_t)n0 * DIM);
    f32x4* qdst = (f32x4*)(outq + (size_t)(n0 + BATCH) * DIM);
    char* tile = Qbf + (size_t)b * 32768;
    #pragma unroll 4
    for (int it = 0; it < 16; ++it) {
        const int L = it * 256 + t;          // 0..4095
        const int r = L >> 6, h = L & 63;
        f32x4 v = qsrc[(size_t)r * 64 + h];
        if (n0 + r < QUEUE - BATCH)
            __builtin_nontemporal_store(v, qdst + (size_t)r * 64 + h);
        short4 bb;
        bb.x = (short)f2bf(v.x); bb.y = (short)f2bf(v.y);
        bb.z = (short)f2bf(v.z); bb.w = (short)f2bf(v.w);
        const int c16 = h >> 1, hf = h & 1;
        *(short4*)(tile + r * 512 + ((c16 ^ (r & 31)) << 4) + hf * 8) = bb;
    }
}

// ---------------- k2: pure bf16 MFMA GEMM filter ----------------
// Grid 1024 = 4 m-strips x 256 n-chunks (256 rows = 4 x 64-row tiles, dbuf). Block =
// 256 thr = 4 waves; wave w: m-rows [s*256 + w*64, +64), pfr[4][8] resident (128 VGPR).
// Staging: global_load_lds 16B from pre-swizzled Qbf -> LDS linear copy IS the swizzled
// image. Inner loop: 4 ds_read_b128 + 16 MFMA per ks. C rows = n (q*4+reg), cols = m (lr).
__device__ __forceinline__ void k2_stage_async(const char* __restrict__ tile,
                                               char* Bsb, int t)
{
    #pragma unroll
    for (int it = 0; it < 8; ++it) {
        const int L = it * 256 + t;          // 0..2047 chunks of 16B
        __builtin_amdgcn_global_load_lds(
            (const __attribute__((address_space(1))) unsigned int*)(tile + (size_t)L * 16),
            (__attribute__((address_space(3))) unsigned int*)(Bsb + L * 16), 16, 0, 0);
    }
}

__global__ __launch_bounds__(256, 2)
void k2_mfma(const unsigned short* __restrict__ PhiF, const char* __restrict__ Qbf,
             float* __restrict__ cand)
{
    __shared__ __align__(16) char Bs[2][32768];
    const int bid = blockIdx.x;      // 0..1023
    const int s = bid >> 8;          // m-strip 0..3
    const int c = bid & 255;         // n-chunk 0..255
    const int t  = threadIdx.x;
    const int w  = t >> 6, lane = t & 63;
    const int lr = lane & 15, q = lane >> 4;
    const int mbase = s * 256 + w * 64;
    const char* chunkbase = Qbf + (size_t)(c * 4) * 32768;

    // ---- preload P fragments: 64 m-rows x K=256 resident; coalesced from PhiF
    bf16x8 pfr[4][8];
    {
        const char* Pw = (const char*)PhiF;
        const int mt16b = mbase >> 4;        // base 16-row tile index
        #pragma unroll
        for (int mj = 0; mj < 4; ++mj)
            #pragma unroll
            for (int ks = 0; ks < 8; ++ks)
                pfr[mj][ks] = *(const bf16x8*)(Pw + ((size_t)((mt16b + mj) * 8 + ks) * 64 + lane) * 16);
    }

    k2_stage_async(chunkbase, Bs[0], t);
    __syncthreads();

    for (int tl = 0; tl < 4; ++tl) {
        if (tl < 3)
            k2_stage_async(chunkbase + (size_t)(tl + 1) * 32768, Bs[(tl + 1) & 1], t);

        char* Bsb = Bs[tl & 1];
        f32x4 acc[4][4];                 // [ni][mj]
        #pragma unroll
        for (int i = 0; i < 4; ++i)
            #pragma unroll
            for (int j = 0; j < 4; ++j) acc[i][j] = (f32x4){0.f, 0.f, 0.f, 0.f};

        #pragma unroll
        for (int ks = 0; ks < 8; ++ks) {
            bf16x8 qf[4];
            #pragma unroll
            for (int ni = 0; ni < 4; ++ni) {
                const int r = ni * 16 + lr;
                const int c16 = ks * 4 + q;
                qf[ni] = *(const bf16x8*)(Bsb + r * 512 + ((c16 ^ (r & 31)) << 4));
            }
            #pragma unroll
            for (int ni = 0; ni < 4; ++ni)
                #pragma unroll
                for (int mj = 0; mj < 4; ++mj)
                    acc[ni][mj] = __builtin_amdgcn_mfma_f32_16x16x32_bf16(qf[ni], pfr[mj][ks], acc[ni][mj], 0, 0, 0);
        }

        // ---- epilogue: per (m, 32-n-group) max. n in-lane (+q), m across 16 lanes.
        #pragma unroll
        for (int mj = 0; mj < 4; ++mj) {
            #pragma unroll
            for (int gl = 0; gl < 2; ++gl) {
                f32x4 va = acc[2 * gl][mj], vb = acc[2 * gl + 1][mj];
                float mx = fmaxf(fmaxf(fmaxf(va[0], va[1]), fmaxf(va[2], va[3])),
                                 fmaxf(fmaxf(vb[0], vb[1]), fmaxf(vb[2], vb[3])));
                mx = fmaxf(mx, __shfl_xor(mx, 16, 64));
                mx = fmaxf(mx, __shfl_xor(mx, 32, 64));
                if (q == 0)
                    cand[(size_t)(c * 8 + tl * 2 + gl) * MROWS + (mbase + mj * 16 + lr)] = mx;
            }
        }
        __syncthreads();
    }
}

// ---------------- k2b: per-row max over groups (wide, pipelined) ----------------
__global__ void k2b_rowmax(const float* __restrict__ cand, unsigned int* __restrict__ rowmaxU)
{
    const int t  = threadIdx.x;              // 256
    const int ml = t & 63, gs = t >> 6;
    const int mc = blockIdx.x & 15, gc = blockIdx.x >> 4;
    const int m  = mc * 64 + ml;
    const int g0 = gc * 128 + gs * 32;
    float mx = -1e30f;
    #pragma unroll 8
    for (int j = 0; j < 32; ++j)
        mx = fmaxf(mx, cand[(size_t)(g0 + j) * MROWS + m]);
    __shared__ float pm[4][64];
    pm[gs][ml] = mx;
    __syncthreads();
    if (gs == 0) {
        mx = fmaxf(fmaxf(pm[0][ml], pm[1][ml]), fmaxf(pm[2][ml], pm[3][ml]));
        atomicMax(rowmaxU + m, mono_f32(mx));
    }
}

// ---------------- k2c: margin filter -> pair list (wide, pipelined) ----------------
__global__ void k2c_filter(const float* __restrict__ cand, const unsigned int* __restrict__ rowmaxU,
                           unsigned int* __restrict__ pairs, int* __restrict__ npairs)
{
    const int t  = threadIdx.x;              // 256
    const int ml = t & 63, gs = t >> 6;
    const int mc = blockIdx.x & 15, gc = blockIdx.x >> 4;
    const int m  = mc * 64 + ml;
    const int g0 = gc * 128 + gs * 32;
    const float thr = unmono_f32(rowmaxU[m]) - MARGIN;
    #pragma unroll 8
    for (int j = 0; j < 32; ++j) {
        if (cand[(size_t)(g0 + j) * MROWS + m] >= thr) {
            int p = atomicAdd(npairs, 1);
            pairs[p] = ((unsigned int)m << 16) | (unsigned int)(g0 + j);
        }
    }
}

// ---------------- k2d: exact fp32 rescore, one wave per (row,group) ----------------
__global__ __launch_bounds__(256, 4)
void k2d_rescore(const unsigned int* __restrict__ pairs, const int* __restrict__ npairs,
                 const float* __restrict__ Pn, const float* __restrict__ queue,
                 unsigned long long* __restrict__ rowfinal)
{
    const int t = threadIdx.x, w = t >> 6, lane = t & 63;
    const int n = *npairs;
    const int col_l = lane & 31, half = lane >> 5;
    for (int p = blockIdx.x * 4 + w; p < n; p += gridDim.x * 4) {
        const unsigned int pr = pairs[p];
        const int row = pr >> 16, g = pr & 0xffff;
        const int col = g * 32 + col_l;
        const float4* qp = (const float4*)(queue + (size_t)col * DIM + half * 128);
        const float4* pp = (const float4*)(Pn + (size_t)row * DIM + half * 128);
        float4 sv = {0.f, 0.f, 0.f, 0.f};
        #pragma unroll 8
        for (int j = 0; j < 32; ++j) {
            float4 a = pp[j], b = qp[j];
            sv.x = fmaf(a.x, b.x, sv.x); sv.y = fmaf(a.y, b.y, sv.y);
            sv.z = fmaf(a.z, b.z, sv.z); sv.w = fmaf(a.w, b.w, sv.w);
        }
        float s = (sv.x + sv.y) + (sv.z + sv.w);
        s += __shfl_xor(s, 32, 64);                       // combine k-halves
        unsigned long long best = ((unsigned long long)mono_f32(s) << 32)
                                | (unsigned int)(65535 - col);
        #pragma unroll
        for (int off = 1; off <= 16; off <<= 1) {
            unsigned long long o = __shfl_xor(best, off, 64);
            best = best > o ? best : o;
        }
        if (lane == 0) atomicMax(rowfinal + row, best);
    }
}

// ---------------- k3: S1/S2 similarity matrices (8 rows x 256-col half per block) --------
__global__ void k3_sim(const unsigned long long* __restrict__ rowfinal,
                       const float* __restrict__ queue,
                       const float* __restrict__ PnT, float* __restrict__ S)
{
    const int b  = blockIdx.x;       // 0..255
    const int rb = (b >> 1) * 8;     // 0..1016 (rows of [nn1;nn2])
    const int ch = b & 1;            // column half
    const int tid = threadIdx.x;     // 256
    const int which = (rb < BATCH) ? 0 : 1;
    const int colbase = which ? 0 : BATCH;    // S1 vs p2 (cols 512..1023), S2 vs p1 (0..511)
    const int col = colbase + ch * 256 + tid;
    __shared__ float nnv[8][DIM];
    #pragma unroll
    for (int j = 0; j < 8; ++j) {
        const int idx = 65535 - (int)(rowfinal[rb + j] & 0xFFFFull);
        nnv[j][tid] = queue[(size_t)idx * DIM + tid];
    }
    __syncthreads();
    float acc[8];
    #pragma unroll
    for (int j = 0; j < 8; ++j) acc[j] = 0.f;
    for (int k4 = 0; k4 < 64; ++k4) {
        float4 nv[8];
        #pragma unroll
        for (int j = 0; j < 8; ++j) nv[j] = ((const float4*)nnv[j])[k4];
        #pragma unroll
        for (int kk = 0; kk < 4; ++kk) {
            const int k = k4 * 4 + kk;
            const float v0 = PnT[(size_t)k * MROWS + col];
            #pragma unroll
            for (int j = 0; j < 8; ++j) {
                const float nj = ((const float*)&nv[j])[kk];
                acc[j] = fmaf(nj, v0, acc[j]);
            }
        }
    }
    const int i0 = rb & (BATCH - 1);
    float* Sout = S + (size_t)which * (BATCH * BATCH);
    #pragma unroll
    for (int j = 0; j < 8; ++j)
        Sout[(size_t)(i0 + j) * BATCH + ch * 256 + tid] = acc[j] * 10.0f;
}

// ---------------- k4: loss ----------------
__global__ void k4_loss(const float* __restrict__ S, float* __restrict__ loss)
{
    const int r = blockIdx.x;        // 0..2047
    const int tid = threadIdx.x;     // 256
    const int grp = r >> 9;
    const int i = r & 511;
    const float* M = S + (size_t)(grp >> 1) * (BATCH * BATCH);
    float x0, x1;
    if (!(grp & 1)) { x0 = M[(size_t)i * BATCH + tid];  x1 = M[(size_t)i * BATCH + tid + 256]; }
    else            { x0 = M[(size_t)tid * BATCH + i];  x1 = M[(size_t)(tid + 256) * BATCH + i]; }
    const float diag = M[(size_t)i * BATCH + i];
    float mx = fmaxf(x0, x1);
    #pragma unroll
    for (int off = 1; off < 64; off <<= 1) mx = fmaxf(mx, __shfl_xor(mx, off, 64));
    __shared__ float redm[4], reds[4];
    if ((tid & 63) == 0) redm[tid >> 6] = mx;
    __syncthreads();
    mx = fmaxf(fmaxf(redm[0], redm[1]), fmaxf(redm[2], redm[3]));
    float e = __expf(x0 - mx) + __expf(x1 - mx);
    #pragma unroll
    for (int off = 1; off < 64; off <<= 1) e += __shfl_xor(e, off, 64);
    if ((tid & 63) == 0) reds[tid >> 6] = e;
    __syncthreads();
    if (tid == 0)
        loss[r] = mx + logf(reds[0] + reds[1] + reds[2] + reds[3]) - diag;
}

// ---------------- launcher ----------------
extern "C" void kernel_launch(void* const* d_in, const int* in_sizes, int n_in,
                              void* d_out, int out_size, void* d_ws, size_t ws_size,
                              hipStream_t stream)
{
    const float* p1    = (const float*)d_in[0];
    const float* p2    = (const float*)d_in[1];
    const float* queue = (const float*)d_in[2];
    float* out  = (float*)d_out;
    float* loss = out;
    float* outq = out + 4 * BATCH;

    // Workspace (~44.5 MB). Qbf (32 MB) aliases pairs: Qbf dead after k2, pairs born in k2c.
    char* w = (char*)d_ws;
    float* cand = (float*)w;                               w += (size_t)NGRP * MROWS * 4;   // 8 MB [g][m]
    unsigned long long* rowfinal = (unsigned long long*)w; w += MROWS * 8;
    unsigned int* rowmaxU = (unsigned int*)w;              w += MROWS * 4;
    float* Pn  = (float*)w;                                w += (size_t)MROWS * DIM * 4;    // 1 MB
    float* PnT = (float*)w;                                w += (size_t)MROWS * DIM * 4;    // 1 MB
    unsigned short* PhiF = (unsigned short*)w;             w += (size_t)MROWS * DIM * 2;    // 0.5 MB
    float* S = (float*)w;                                  w += (size_t)2 * BATCH * BATCH * 4; // 2 MB
    int* npairs = (int*)w;                                 w += 16;
    char* Qbf = w;                                         // 32 MB (QUEUE*DIM*2)
    unsigned int* pairs = (unsigned int*)Qbf;              // alias (see above)

    hipLaunchKernelGGL(k1_norm,     dim3(MROWS), dim3(64),  0, stream, p1, p2, Pn, PnT, PhiF, outq,
                       npairs, rowmaxU, rowfinal);
    hipLaunchKernelGGL(k0_prep,     dim3(QUEUE / 64), dim3(256), 0, stream, queue, outq, Qbf);
    hipLaunchKernelGGL(k2_mfma,     dim3(1024), dim3(256), 0, stream, PhiF, Qbf, cand);
    hipLaunchKernelGGL(k2b_rowmax,  dim3(256),   dim3(256), 0, stream, cand, rowmaxU);
    hipLaunchKernelGGL(k2c_filter,  dim3(256),   dim3(256), 0, stream, cand, rowmaxU, pairs, npairs);
    hipLaunchKernelGGL(k2d_rescore, dim3(512),   dim3(256), 0, stream, pairs, npairs, Pn, queue, rowfinal);
    hipLaunchKernelGGL(k3_sim,      dim3(256),   dim3(256), 0, stream, rowfinal, queue, PnT, S);
    hipLaunchKernelGGL(k4_loss,     dim3(4 * BATCH), dim3(256), 0, stream, S, loss);
}

// Round 5
// 240.431 us; speedup vs baseline: 1.1054x; 1.0215x over previous
//
#include <hip/hip_runtime.h>
#include <stdint.h>

// NNCLR forward on MI355X — round 10.
// Changes vs round 9 (245.6 us, k2 fixed; k0_prep now top at ~43 us):
//  * k0_prep: 32B/thread/iter (2x f32x4 loads -> 2 nt outq stores + ONE 16B Qbf store,
//    was 2x 8B), grid 1024 -> 2048 (32-row slabs) for 2x waves. Latency/width fix;
//    counters showed 3.7 TB/s eff, VALU 4.7%, occ 32% -> not BW-saturated.
//  * k2_mfma: XCD-sharing bid remap (c=(bid>>5)*8+(bid&7), s=(bid>>3)&3) so the 4
//    strips reading the same Qbf chunk land on the SAME XCD adjacent in time ->
//    Qbf L3 reads 128 MB -> ~32 MB (3/4 become L2 hits).
//  * k2b fused into k2's epilogue (running rowmx[4] + one atomicMax per m per block);
//    k2b kernel deleted (-8 MB cand re-read, -1 launch).
//  * k1 / k2c / k2d / k3 / k4 unchanged (passed, absmax 0).

#define BATCH  512
#define DIM    256
#define QUEUE  65536
#define MROWS  1024
#define NGRP   2048          // 65536 / 32
#define MARGIN 0.01f

typedef short bf16x8 __attribute__((ext_vector_type(8)));
typedef float f32x4  __attribute__((ext_vector_type(4)));

__device__ __forceinline__ unsigned int mono_f32(float f) {
    unsigned int u = __float_as_uint(f);
    return (u & 0x80000000u) ? ~u : (u | 0x80000000u);
}
__device__ __forceinline__ float unmono_f32(unsigned int m) {
    unsigned int u = (m & 0x80000000u) ? (m ^ 0x80000000u) : ~m;
    return __uint_as_float(u);
}
__device__ __forceinline__ unsigned short f2bf(float f) {   // RNE fp32->bf16
    unsigned int u = __float_as_uint(f);
    return (unsigned short)((u + 0x7fffu + ((u >> 16) & 1u)) >> 16);
}

// ---------------- k1: normalize + PhiF (fragment layout) + ws init ----------------
// PhiF 16B-chunk index for (row r, k-chunk c = k/8): ((r>>4)*8 + (c>>2))*64 + (c&3)*16 + (r&15)
// so a wave's pfr load (lane = q*16+lr) is one coalesced 1KB b128 read per (mt16, ks).
__global__ void k1_norm(const float* __restrict__ p1, const float* __restrict__ p2,
                        float* __restrict__ Pn, float* __restrict__ PnT,
                        unsigned short* __restrict__ PhiF, float* __restrict__ outq,
                        int* __restrict__ npairs, unsigned int* __restrict__ rowmaxU,
                        unsigned long long* __restrict__ rowfinal)
{
    const int r = blockIdx.x;        // 0..1023
    const int t = threadIdx.x;       // 0..63
    if (t == 0) {                    // stream-ordered init (ws poisoned 0xAA each call)
        rowmaxU[r] = 0u;
        rowfinal[r] = 0ull;
        if (r == 0) *npairs = 0;
    }
    const float* src = (r < BATCH) ? p1 : p2;
    const int row = (r < BATCH) ? r : r - BATCH;
    float4 v = ((const float4*)(src + (size_t)row * DIM))[t];
    float sq = v.x*v.x + v.y*v.y + v.z*v.z + v.w*v.w;
    #pragma unroll
    for (int off = 32; off; off >>= 1) sq += __shfl_xor(sq, off, 64);
    sq = fmaxf(sq, 1e-12f);
    float s = rsqrtf(sq);
    s = s * (1.5f - 0.5f * sq * s * s);
    v.x *= s; v.y *= s; v.z *= s; v.w *= s;
    ((float4*)(Pn + (size_t)r * DIM))[t] = v;
    const int k = t * 4;
    PnT[(size_t)(k + 0) * MROWS + r] = v.x;
    PnT[(size_t)(k + 1) * MROWS + r] = v.y;
    PnT[(size_t)(k + 2) * MROWS + r] = v.z;
    PnT[(size_t)(k + 3) * MROWS + r] = v.w;
    short4 b;
    b.x = (short)f2bf(v.x); b.y = (short)f2bf(v.y);
    b.z = (short)f2bf(v.z); b.w = (short)f2bf(v.w);
    // fragment-ready: chunk c = t>>1 (8 bf16), this thread holds half (t&1)
    {
        const int c = t >> 1;
        const int idx = ((r >> 4) * 8 + (c >> 2)) * 64 + (c & 3) * 16 + (r & 15);
        *(short4*)((char*)PhiF + (size_t)idx * 16 + (t & 1) * 8) = b;
    }
    if (r < BATCH) ((float4*)(outq + (size_t)r * DIM))[t] = v;  // new_queue[0:512] = p1n
}

// ---------------- k0: queue -> outq FIFO copy + Qbf (pre-swizzled bf16 tile image) -----
// 2048 blocks, one per 32-row slab (half of a 64-row Qbf tile). Per thread/iter: 32B in
// (2x f32x4), 32B nt out (outq), 16B out (Qbf). Qbf tile b>>1 at byte (b>>1)*32768;
// 16B chunk (rr, c16) at rr*512 + ((c16 ^ (rr & 31)) << 4) — the LDS image k2 reads.
__global__ __launch_bounds__(256)
void k0_prep(const float* __restrict__ queue, float* __restrict__ outq,
             char* __restrict__ Qbf)
{
    const int b = blockIdx.x;        // 0..2047
    const int t = threadIdx.x;       // 0..255
    const int n0 = b * 32;
    const f32x4* qsrc = (const f32x4*)(queue + (size_t)n0 * DIM);
    f32x4* qdst = (f32x4*)(outq + (size_t)(n0 + BATCH) * DIM);
    char* tile = Qbf + (size_t)(b >> 1) * 32768;
    #pragma unroll
    for (int it = 0; it < 4; ++it) {
        const int L = it * 256 + t;          // 0..1023: 32B chunk id
        const int r = L >> 5;                // local row 0..31
        const int c16 = L & 31;              // 16B bf16-chunk col 0..31
        f32x4 v0 = qsrc[(size_t)r * 64 + c16 * 2];
        f32x4 v1 = qsrc[(size_t)r * 64 + c16 * 2 + 1];
        if (n0 + r < QUEUE - BATCH) {
            __builtin_nontemporal_store(v0, qdst + (size_t)r * 64 + c16 * 2);
            __builtin_nontemporal_store(v1, qdst + (size_t)r * 64 + c16 * 2 + 1);
        }
        bf16x8 bb;
        bb[0] = (short)f2bf(v0.x); bb[1] = (short)f2bf(v0.y);
        bb[2] = (short)f2bf(v0.z); bb[3] = (short)f2bf(v0.w);
        bb[4] = (short)f2bf(v1.x); bb[5] = (short)f2bf(v1.y);
        bb[6] = (short)f2bf(v1.z); bb[7] = (short)f2bf(v1.w);
        const int rr = ((b & 1) << 5) + r;   // row within 64-row tile
        *(bf16x8*)(tile + rr * 512 + ((c16 ^ (rr & 31)) << 4)) = bb;
    }
}

// ---------------- k2: pure bf16 MFMA GEMM filter + fused rowmax ----------------
// Grid 1024; bid remap c=(bid>>5)*8+(bid&7), s=(bid>>3)&3 so the 4 strips sharing a
// Qbf chunk are bids {x,x+8,x+16,x+24} -> same XCD, adjacent dispatch -> L2 sharing.
// Block = 256 thr = 4 waves; wave w: m-rows [s*256 + w*64, +64), pfr[4][8] resident.
// Staging: global_load_lds 16B from pre-swizzled Qbf. Inner: 4 ds_read_b128 + 16 MFMA
// per ks. C rows = n (q*4+reg), cols = m (lr). Epilogue also accumulates per-m rowmax
// across tiles and atomicMax's rowmaxU once per m per block (k2b deleted).
__device__ __forceinline__ void k2_stage_async(const char* __restrict__ tile,
                                               char* Bsb, int t)
{
    #pragma unroll
    for (int it = 0; it < 8; ++it) {
        const int L = it * 256 + t;          // 0..2047 chunks of 16B
        __builtin_amdgcn_global_load_lds(
            (const __attribute__((address_space(1))) unsigned int*)(tile + (size_t)L * 16),
            (__attribute__((address_space(3))) unsigned int*)(Bsb + L * 16), 16, 0, 0);
    }
}

__global__ __launch_bounds__(256, 2)
void k2_mfma(const unsigned short* __restrict__ PhiF, const char* __restrict__ Qbf,
             float* __restrict__ cand, unsigned int* __restrict__ rowmaxU)
{
    __shared__ __align__(16) char Bs[2][32768];
    const int bid = blockIdx.x;      // 0..1023
    const int c = (bid >> 5) * 8 + (bid & 7);   // n-chunk 0..255
    const int s = (bid >> 3) & 3;               // m-strip 0..3
    const int t  = threadIdx.x;
    const int w  = t >> 6, lane = t & 63;
    const int lr = lane & 15, q = lane >> 4;
    const int mbase = s * 256 + w * 64;
    const char* chunkbase = Qbf + (size_t)(c * 4) * 32768;

    // ---- preload P fragments: 64 m-rows x K=256 resident; coalesced from PhiF
    bf16x8 pfr[4][8];
    {
        const char* Pw = (const char*)PhiF;
        const int mt16b = mbase >> 4;        // base 16-row tile index
        #pragma unroll
        for (int mj = 0; mj < 4; ++mj)
            #pragma unroll
            for (int ks = 0; ks < 8; ++ks)
                pfr[mj][ks] = *(const bf16x8*)(Pw + ((size_t)((mt16b + mj) * 8 + ks) * 64 + lane) * 16);
    }

    k2_stage_async(chunkbase, Bs[0], t);
    __syncthreads();

    float rowmx[4] = {-1e30f, -1e30f, -1e30f, -1e30f};

    for (int tl = 0; tl < 4; ++tl) {
        if (tl < 3)
            k2_stage_async(chunkbase + (size_t)(tl + 1) * 32768, Bs[(tl + 1) & 1], t);

        char* Bsb = Bs[tl & 1];
        f32x4 acc[4][4];                 // [ni][mj]
        #pragma unroll
        for (int i = 0; i < 4; ++i)
            #pragma unroll
            for (int j = 0; j < 4; ++j) acc[i][j] = (f32x4){0.f, 0.f, 0.f, 0.f};

        #pragma unroll
        for (int ks = 0; ks < 8; ++ks) {
            bf16x8 qf[4];
            #pragma unroll
            for (int ni = 0; ni < 4; ++ni) {
                const int r = ni * 16 + lr;
                const int c16 = ks * 4 + q;
                qf[ni] = *(const bf16x8*)(Bsb + r * 512 + ((c16 ^ (r & 31)) << 4));
            }
            #pragma unroll
            for (int ni = 0; ni < 4; ++ni)
                #pragma unroll
                for (int mj = 0; mj < 4; ++mj)
                    acc[ni][mj] = __builtin_amdgcn_mfma_f32_16x16x32_bf16(qf[ni], pfr[mj][ks], acc[ni][mj], 0, 0, 0);
        }

        // ---- epilogue: per (m, 32-n-group) max. n in-lane (+q), m across 16 lanes.
        #pragma unroll
        for (int mj = 0; mj < 4; ++mj) {
            #pragma unroll
            for (int gl = 0; gl < 2; ++gl) {
                f32x4 va = acc[2 * gl][mj], vb = acc[2 * gl + 1][mj];
                float mx = fmaxf(fmaxf(fmaxf(va[0], va[1]), fmaxf(va[2], va[3])),
                                 fmaxf(fmaxf(vb[0], vb[1]), fmaxf(vb[2], vb[3])));
                mx = fmaxf(mx, __shfl_xor(mx, 16, 64));
                mx = fmaxf(mx, __shfl_xor(mx, 32, 64));
                rowmx[mj] = fmaxf(rowmx[mj], mx);
                if (q == 0)
                    cand[(size_t)(c * 8 + tl * 2 + gl) * MROWS + (mbase + mj * 16 + lr)] = mx;
            }
        }
        __syncthreads();
    }

    // ---- fused k2b: one atomic per m per block
    if (q == 0) {
        #pragma unroll
        for (int mj = 0; mj < 4; ++mj)
            atomicMax(rowmaxU + mbase + mj * 16 + lr, mono_f32(rowmx[mj]));
    }
}

// ---------------- k2c: margin filter -> pair list (wide, pipelined) ----------------
__global__ void k2c_filter(const float* __restrict__ cand, const unsigned int* __restrict__ rowmaxU,
                           unsigned int* __restrict__ pairs, int* __restrict__ npairs)
{
    const int t  = threadIdx.x;              // 256
    const int ml = t & 63, gs = t >> 6;
    const int mc = blockIdx.x & 15, gc = blockIdx.x >> 4;
    const int m  = mc * 64 + ml;
    const int g0 = gc * 128 + gs * 32;
    const float thr = unmono_f32(rowmaxU[m]) - MARGIN;
    #pragma unroll 8
    for (int j = 0; j < 32; ++j) {
        if (cand[(size_t)(g0 + j) * MROWS + m] >= thr) {
            int p = atomicAdd(npairs, 1);
            pairs[p] = ((unsigned int)m << 16) | (unsigned int)(g0 + j);
        }
    }
}

// ---------------- k2d: exact fp32 rescore, one wave per (row,group) ----------------
__global__ __launch_bounds__(256, 4)
void k2d_rescore(const unsigned int* __restrict__ pairs, const int* __restrict__ npairs,
                 const float* __restrict__ Pn, const float* __restrict__ queue,
                 unsigned long long* __restrict__ rowfinal)
{
    const int t = threadIdx.x, w = t >> 6, lane = t & 63;
    const int n = *npairs;
    const int col_l = lane & 31, half = lane >> 5;
    for (int p = blockIdx.x * 4 + w; p < n; p += gridDim.x * 4) {
        const unsigned int pr = pairs[p];
        const int row = pr >> 16, g = pr & 0xffff;
        const int col = g * 32 + col_l;
        const float4* qp = (const float4*)(queue + (size_t)col * DIM + half * 128);
        const float4* pp = (const float4*)(Pn + (size_t)row * DIM + half * 128);
        float4 sv = {0.f, 0.f, 0.f, 0.f};
        #pragma unroll 8
        for (int j = 0; j < 32; ++j) {
            float4 a = pp[j], b = qp[j];
            sv.x = fmaf(a.x, b.x, sv.x); sv.y = fmaf(a.y, b.y, sv.y);
            sv.z = fmaf(a.z, b.z, sv.z); sv.w = fmaf(a.w, b.w, sv.w);
        }
        float s = (sv.x + sv.y) + (sv.z + sv.w);
        s += __shfl_xor(s, 32, 64);                       // combine k-halves
        unsigned long long best = ((unsigned long long)mono_f32(s) << 32)
                                | (unsigned int)(65535 - col);
        #pragma unroll
        for (int off = 1; off <= 16; off <<= 1) {
            unsigned long long o = __shfl_xor(best, off, 64);
            best = best > o ? best : o;
        }
        if (lane == 0) atomicMax(rowfinal + row, best);
    }
}

// ---------------- k3: S1/S2 similarity matrices (8 rows x 256-col half per block) --------
__global__ void k3_sim(const unsigned long long* __restrict__ rowfinal,
                       const float* __restrict__ queue,
                       const float* __restrict__ PnT, float* __restrict__ S)
{
    const int b  = blockIdx.x;       // 0..255
    const int rb = (b >> 1) * 8;     // 0..1016 (rows of [nn1;nn2])
    const int ch = b & 1;            // column half
    const int tid = threadIdx.x;     // 256
    const int which = (rb < BATCH) ? 0 : 1;
    const int colbase = which ? 0 : BATCH;    // S1 vs p2 (cols 512..1023), S2 vs p1 (0..511)
    const int col = colbase + ch * 256 + tid;
    __shared__ float nnv[8][DIM];
    #pragma unroll
    for (int j = 0; j < 8; ++j) {
        const int idx = 65535 - (int)(rowfinal[rb + j] & 0xFFFFull);
        nnv[j][tid] = queue[(size_t)idx * DIM + tid];
    }
    __syncthreads();
    float acc[8];
    #pragma unroll
    for (int j = 0; j < 8; ++j) acc[j] = 0.f;
    for (int k4 = 0; k4 < 64; ++k4) {
        float4 nv[8];
        #pragma unroll
        for (int j = 0; j < 8; ++j) nv[j] = ((const float4*)nnv[j])[k4];
        #pragma unroll
        for (int kk = 0; kk < 4; ++kk) {
            const int k = k4 * 4 + kk;
            const float v0 = PnT[(size_t)k * MROWS + col];
            #pragma unroll
            for (int j = 0; j < 8; ++j) {
                const float nj = ((const float*)&nv[j])[kk];
                acc[j] = fmaf(nj, v0, acc[j]);
            }
        }
    }
    const int i0 = rb & (BATCH - 1);
    float* Sout = S + (size_t)which * (BATCH * BATCH);
    #pragma unroll
    for (int j = 0; j < 8; ++j)
        Sout[(size_t)(i0 + j) * BATCH + ch * 256 + tid] = acc[j] * 10.0f;
}

// ---------------- k4: loss ----------------
__global__ void k4_loss(const float* __restrict__ S, float* __restrict__ loss)
{
    const int r = blockIdx.x;        // 0..2047
    const int tid = threadIdx.x;     // 256
    const int grp = r >> 9;
    const int i = r & 511;
    const float* M = S + (size_t)(grp >> 1) * (BATCH * BATCH);
    float x0, x1;
    if (!(grp & 1)) { x0 = M[(size_t)i * BATCH + tid];  x1 = M[(size_t)i * BATCH + tid + 256]; }
    else            { x0 = M[(size_t)tid * BATCH + i];  x1 = M[(size_t)(tid + 256) * BATCH + i]; }
    const float diag = M[(size_t)i * BATCH + i];
    float mx = fmaxf(x0, x1);
    #pragma unroll
    for (int off = 1; off < 64; off <<= 1) mx = fmaxf(mx, __shfl_xor(mx, off, 64));
    __shared__ float redm[4], reds[4];
    if ((tid & 63) == 0) redm[tid >> 6] = mx;
    __syncthreads();
    mx = fmaxf(fmaxf(redm[0], redm[1]), fmaxf(redm[2], redm[3]));
    float e = __expf(x0 - mx) + __expf(x1 - mx);
    #pragma unroll
    for (int off = 1; off < 64; off <<= 1) e += __shfl_xor(e, off, 64);
    if ((tid & 63) == 0) reds[tid >> 6] = e;
    __syncthreads();
    if (tid == 0)
        loss[r] = mx + logf(reds[0] + reds[1] + reds[2] + reds[3]) - diag;
}

// ---------------- launcher ----------------
extern "C" void kernel_launch(void* const* d_in, const int* in_sizes, int n_in,
                              void* d_out, int out_size, void* d_ws, size_t ws_size,
                              hipStream_t stream)
{
    const float* p1    = (const float*)d_in[0];
    const float* p2    = (const float*)d_in[1];
    const float* queue = (const float*)d_in[2];
    float* out  = (float*)d_out;
    float* loss = out;
    float* outq = out + 4 * BATCH;

    // Workspace (~44.5 MB). Qbf (32 MB) aliases pairs: Qbf dead after k2, pairs born in k2c.
    char* w = (char*)d_ws;
    float* cand = (float*)w;                               w += (size_t)NGRP * MROWS * 4;   // 8 MB [g][m]
    unsigned long long* rowfinal = (unsigned long long*)w; w += MROWS * 8;
    unsigned int* rowmaxU = (unsigned int*)w;              w += MROWS * 4;
    float* Pn  = (float*)w;                                w += (size_t)MROWS * DIM * 4;    // 1 MB
    float* PnT = (float*)w;                                w += (size_t)MROWS * DIM * 4;    // 1 MB
    unsigned short* PhiF = (unsigned short*)w;             w += (size_t)MROWS * DIM * 2;    // 0.5 MB
    float* S = (float*)w;                                  w += (size_t)2 * BATCH * BATCH * 4; // 2 MB
    int* npairs = (int*)w;                                 w += 16;
    char* Qbf = w;                                         // 32 MB (QUEUE*DIM*2)
    unsigned int* pairs = (unsigned int*)Qbf;              // alias (see above)

    hipLaunchKernelGGL(k1_norm,     dim3(MROWS), dim3(64),  0, stream, p1, p2, Pn, PnT, PhiF, outq,
                       npairs, rowmaxU, rowfinal);
    hipLaunchKernelGGL(k0_prep,     dim3(QUEUE / 32), dim3(256), 0, stream, queue, outq, Qbf);
    hipLaunchKernelGGL(k2_mfma,     dim3(1024), dim3(256), 0, stream, PhiF, Qbf, cand, rowmaxU);
    hipLaunchKernelGGL(k2c_filter,  dim3(256),   dim3(256), 0, stream, cand, rowmaxU, pairs, npairs);
    hipLaunchKernelGGL(k2d_rescore, dim3(512),   dim3(256), 0, stream, pairs, npairs, Pn, queue, rowfinal);
    hipLaunchKernelGGL(k3_sim,      dim3(256),   dim3(256), 0, stream, rowfinal, queue, PnT, S);
    hipLaunchKernelGGL(k4_loss,     dim3(4 * BATCH), dim3(256), 0, stream, S, loss);
}

// Round 6
// 232.346 us; speedup vs baseline: 1.1438x; 1.0348x over previous
//
#include <hip/hip_runtime.h>
#include <stdint.h>

// NNCLR forward on MI355X — round 11.
// Changes vs round 10 (240.4 us):
//  * k0_prep: REMOVED non-temporal hint on outq stores. Evidence: k0 pinned at 3.35 TB/s
//    across two structurally different rounds, while the harness's fillBufferAligned does
//    6.24 TB/s plain cached writes on the same chip. NT bypasses L2 write-combining ->
//    16B-granule HBM transactions. Also: load-all-8-f32x4-then-store (was serialized at
//    VGPR_Count=20, one load-pair in flight).
//  * k1 / k2 / k2c / k2d / k3 / k4 unchanged (passed, absmax 0).

#define BATCH  512
#define DIM    256
#define QUEUE  65536
#define MROWS  1024
#define NGRP   2048          // 65536 / 32
#define MARGIN 0.01f

typedef short bf16x8 __attribute__((ext_vector_type(8)));
typedef float f32x4  __attribute__((ext_vector_type(4)));

__device__ __forceinline__ unsigned int mono_f32(float f) {
    unsigned int u = __float_as_uint(f);
    return (u & 0x80000000u) ? ~u : (u | 0x80000000u);
}
__device__ __forceinline__ float unmono_f32(unsigned int m) {
    unsigned int u = (m & 0x80000000u) ? (m ^ 0x80000000u) : ~m;
    return __uint_as_float(u);
}
__device__ __forceinline__ unsigned short f2bf(float f) {   // RNE fp32->bf16
    unsigned int u = __float_as_uint(f);
    return (unsigned short)((u + 0x7fffu + ((u >> 16) & 1u)) >> 16);
}

// ---------------- k1: normalize + PhiF (fragment layout) + ws init ----------------
// PhiF 16B-chunk index for (row r, k-chunk c = k/8): ((r>>4)*8 + (c>>2))*64 + (c&3)*16 + (r&15)
// so a wave's pfr load (lane = q*16+lr) is one coalesced 1KB b128 read per (mt16, ks).
__global__ void k1_norm(const float* __restrict__ p1, const float* __restrict__ p2,
                        float* __restrict__ Pn, float* __restrict__ PnT,
                        unsigned short* __restrict__ PhiF, float* __restrict__ outq,
                        int* __restrict__ npairs, unsigned int* __restrict__ rowmaxU,
                        unsigned long long* __restrict__ rowfinal)
{
    const int r = blockIdx.x;        // 0..1023
    const int t = threadIdx.x;       // 0..63
    if (t == 0) {                    // stream-ordered init (ws poisoned 0xAA each call)
        rowmaxU[r] = 0u;
        rowfinal[r] = 0ull;
        if (r == 0) *npairs = 0;
    }
    const float* src = (r < BATCH) ? p1 : p2;
    const int row = (r < BATCH) ? r : r - BATCH;
    float4 v = ((const float4*)(src + (size_t)row * DIM))[t];
    float sq = v.x*v.x + v.y*v.y + v.z*v.z + v.w*v.w;
    #pragma unroll
    for (int off = 32; off; off >>= 1) sq += __shfl_xor(sq, off, 64);
    sq = fmaxf(sq, 1e-12f);
    float s = rsqrtf(sq);
    s = s * (1.5f - 0.5f * sq * s * s);
    v.x *= s; v.y *= s; v.z *= s; v.w *= s;
    ((float4*)(Pn + (size_t)r * DIM))[t] = v;
    const int k = t * 4;
    PnT[(size_t)(k + 0) * MROWS + r] = v.x;
    PnT[(size_t)(k + 1) * MROWS + r] = v.y;
    PnT[(size_t)(k + 2) * MROWS + r] = v.z;
    PnT[(size_t)(k + 3) * MROWS + r] = v.w;
    short4 b;
    b.x = (short)f2bf(v.x); b.y = (short)f2bf(v.y);
    b.z = (short)f2bf(v.z); b.w = (short)f2bf(v.w);
    // fragment-ready: chunk c = t>>1 (8 bf16), this thread holds half (t&1)
    {
        const int c = t >> 1;
        const int idx = ((r >> 4) * 8 + (c >> 2)) * 64 + (c & 3) * 16 + (r & 15);
        *(short4*)((char*)PhiF + (size_t)idx * 16 + (t & 1) * 8) = b;
    }
    if (r < BATCH) ((float4*)(outq + (size_t)r * DIM))[t] = v;  // new_queue[0:512] = p1n
}

// ---------------- k0: queue -> outq FIFO copy + Qbf (pre-swizzled bf16 tile image) -----
// 2048 blocks, one per 32-row slab (half of a 64-row Qbf tile). Phase 1: issue all 8
// f32x4 loads (full MLP). Phase 2: plain (cached) outq stores + one 16B Qbf store per
// 32B chunk. Qbf tile b>>1 at byte (b>>1)*32768; 16B chunk (rr, c16) at
// rr*512 + ((c16 ^ (rr & 31)) << 4) — the LDS image k2 reads.
__global__ __launch_bounds__(256)
void k0_prep(const float* __restrict__ queue, float* __restrict__ outq,
             char* __restrict__ Qbf)
{
    const int b = blockIdx.x;        // 0..2047
    const int t = threadIdx.x;       // 0..255
    const int n0 = b * 32;
    const f32x4* qsrc = (const f32x4*)(queue + (size_t)n0 * DIM);
    f32x4* qdst = (f32x4*)(outq + (size_t)(n0 + BATCH) * DIM);
    char* tile = Qbf + (size_t)(b >> 1) * 32768;

    f32x4 va[8];
    #pragma unroll
    for (int it = 0; it < 4; ++it) {
        const int L = it * 256 + t;          // 0..1023: 32B chunk id
        const int r = L >> 5, c16 = L & 31;
        va[2 * it]     = qsrc[(size_t)r * 64 + c16 * 2];
        va[2 * it + 1] = qsrc[(size_t)r * 64 + c16 * 2 + 1];
    }
    #pragma unroll
    for (int it = 0; it < 4; ++it) {
        const int L = it * 256 + t;
        const int r = L >> 5, c16 = L & 31;
        f32x4 v0 = va[2 * it], v1 = va[2 * it + 1];
        if (n0 + r < QUEUE - BATCH) {
            qdst[(size_t)r * 64 + c16 * 2]     = v0;
            qdst[(size_t)r * 64 + c16 * 2 + 1] = v1;
        }
        bf16x8 bb;
        bb[0] = (short)f2bf(v0.x); bb[1] = (short)f2bf(v0.y);
        bb[2] = (short)f2bf(v0.z); bb[3] = (short)f2bf(v0.w);
        bb[4] = (short)f2bf(v1.x); bb[5] = (short)f2bf(v1.y);
        bb[6] = (short)f2bf(v1.z); bb[7] = (short)f2bf(v1.w);
        const int rr = ((b & 1) << 5) + r;   // row within 64-row tile
        *(bf16x8*)(tile + rr * 512 + ((c16 ^ (rr & 31)) << 4)) = bb;
    }
}

// ---------------- k2: pure bf16 MFMA GEMM filter + fused rowmax ----------------
// Grid 1024; bid remap c=(bid>>5)*8+(bid&7), s=(bid>>3)&3 so the 4 strips sharing a
// Qbf chunk are bids {x,x+8,x+16,x+24} -> same XCD, adjacent dispatch -> L2 sharing.
// Block = 256 thr = 4 waves; wave w: m-rows [s*256 + w*64, +64), pfr[4][8] resident.
// Staging: global_load_lds 16B from pre-swizzled Qbf. Inner: 4 ds_read_b128 + 16 MFMA
// per ks. C rows = n (q*4+reg), cols = m (lr). Epilogue also accumulates per-m rowmax
// across tiles and atomicMax's rowmaxU once per m per block (k2b deleted).
__device__ __forceinline__ void k2_stage_async(const char* __restrict__ tile,
                                               char* Bsb, int t)
{
    #pragma unroll
    for (int it = 0; it < 8; ++it) {
        const int L = it * 256 + t;          // 0..2047 chunks of 16B
        __builtin_amdgcn_global_load_lds(
            (const __attribute__((address_space(1))) unsigned int*)(tile + (size_t)L * 16),
            (__attribute__((address_space(3))) unsigned int*)(Bsb + L * 16), 16, 0, 0);
    }
}

__global__ __launch_bounds__(256, 2)
void k2_mfma(const unsigned short* __restrict__ PhiF, const char* __restrict__ Qbf,
             float* __restrict__ cand, unsigned int* __restrict__ rowmaxU)
{
    __shared__ __align__(16) char Bs[2][32768];
    const int bid = blockIdx.x;      // 0..1023
    const int c = (bid >> 5) * 8 + (bid & 7);   // n-chunk 0..255
    const int s = (bid >> 3) & 3;               // m-strip 0..3
    const int t  = threadIdx.x;
    const int w  = t >> 6, lane = t & 63;
    const int lr = lane & 15, q = lane >> 4;
    const int mbase = s * 256 + w * 64;
    const char* chunkbase = Qbf + (size_t)(c * 4) * 32768;

    // ---- preload P fragments: 64 m-rows x K=256 resident; coalesced from PhiF
    bf16x8 pfr[4][8];
    {
        const char* Pw = (const char*)PhiF;
        const int mt16b = mbase >> 4;        // base 16-row tile index
        #pragma unroll
        for (int mj = 0; mj < 4; ++mj)
            #pragma unroll
            for (int ks = 0; ks < 8; ++ks)
                pfr[mj][ks] = *(const bf16x8*)(Pw + ((size_t)((mt16b + mj) * 8 + ks) * 64 + lane) * 16);
    }

    k2_stage_async(chunkbase, Bs[0], t);
    __syncthreads();

    float rowmx[4] = {-1e30f, -1e30f, -1e30f, -1e30f};

    for (int tl = 0; tl < 4; ++tl) {
        if (tl < 3)
            k2_stage_async(chunkbase + (size_t)(tl + 1) * 32768, Bs[(tl + 1) & 1], t);

        char* Bsb = Bs[tl & 1];
        f32x4 acc[4][4];                 // [ni][mj]
        #pragma unroll
        for (int i = 0; i < 4; ++i)
            #pragma unroll
            for (int j = 0; j < 4; ++j) acc[i][j] = (f32x4){0.f, 0.f, 0.f, 0.f};

        #pragma unroll
        for (int ks = 0; ks < 8; ++ks) {
            bf16x8 qf[4];
            #pragma unroll
            for (int ni = 0; ni < 4; ++ni) {
                const int r = ni * 16 + lr;
                const int c16 = ks * 4 + q;
                qf[ni] = *(const bf16x8*)(Bsb + r * 512 + ((c16 ^ (r & 31)) << 4));
            }
            #pragma unroll
            for (int ni = 0; ni < 4; ++ni)
                #pragma unroll
                for (int mj = 0; mj < 4; ++mj)
                    acc[ni][mj] = __builtin_amdgcn_mfma_f32_16x16x32_bf16(qf[ni], pfr[mj][ks], acc[ni][mj], 0, 0, 0);
        }

        // ---- epilogue: per (m, 32-n-group) max. n in-lane (+q), m across 16 lanes.
        #pragma unroll
        for (int mj = 0; mj < 4; ++mj) {
            #pragma unroll
            for (int gl = 0; gl < 2; ++gl) {
                f32x4 va = acc[2 * gl][mj], vb = acc[2 * gl + 1][mj];
                float mx = fmaxf(fmaxf(fmaxf(va[0], va[1]), fmaxf(va[2], va[3])),
                                 fmaxf(fmaxf(vb[0], vb[1]), fmaxf(vb[2], vb[3])));
                mx = fmaxf(mx, __shfl_xor(mx, 16, 64));
                mx = fmaxf(mx, __shfl_xor(mx, 32, 64));
                rowmx[mj] = fmaxf(rowmx[mj], mx);
                if (q == 0)
                    cand[(size_t)(c * 8 + tl * 2 + gl) * MROWS + (mbase + mj * 16 + lr)] = mx;
            }
        }
        __syncthreads();
    }

    // ---- fused k2b: one atomic per m per block
    if (q == 0) {
        #pragma unroll
        for (int mj = 0; mj < 4; ++mj)
            atomicMax(rowmaxU + mbase + mj * 16 + lr, mono_f32(rowmx[mj]));
    }
}

// ---------------- k2c: margin filter -> pair list (wide, pipelined) ----------------
__global__ void k2c_filter(const float* __restrict__ cand, const unsigned int* __restrict__ rowmaxU,
                           unsigned int* __restrict__ pairs, int* __restrict__ npairs)
{
    const int t  = threadIdx.x;              // 256
    const int ml = t & 63, gs = t >> 6;
    const int mc = blockIdx.x & 15, gc = blockIdx.x >> 4;
    const int m  = mc * 64 + ml;
    const int g0 = gc * 128 + gs * 32;
    const float thr = unmono_f32(rowmaxU[m]) - MARGIN;
    #pragma unroll 8
    for (int j = 0; j < 32; ++j) {
        if (cand[(size_t)(g0 + j) * MROWS + m] >= thr) {
            int p = atomicAdd(npairs, 1);
            pairs[p] = ((unsigned int)m << 16) | (unsigned int)(g0 + j);
        }
    }
}

// ---------------- k2d: exact fp32 rescore, one wave per (row,group) ----------------
__global__ __launch_bounds__(256, 4)
void k2d_rescore(const unsigned int* __restrict__ pairs, const int* __restrict__ npairs,
                 const float* __restrict__ Pn, const float* __restrict__ queue,
                 unsigned long long* __restrict__ rowfinal)
{
    const int t = threadIdx.x, w = t >> 6, lane = t & 63;
    const int n = *npairs;
    const int col_l = lane & 31, half = lane >> 5;
    for (int p = blockIdx.x * 4 + w; p < n; p += gridDim.x * 4) {
        const unsigned int pr = pairs[p];
        const int row = pr >> 16, g = pr & 0xffff;
        const int col = g * 32 + col_l;
        const float4* qp = (const float4*)(queue + (size_t)col * DIM + half * 128);
        const float4* pp = (const float4*)(Pn + (size_t)row * DIM + half * 128);
        float4 sv = {0.f, 0.f, 0.f, 0.f};
        #pragma unroll 8
        for (int j = 0; j < 32; ++j) {
            float4 a = pp[j], b = qp[j];
            sv.x = fmaf(a.x, b.x, sv.x); sv.y = fmaf(a.y, b.y, sv.y);
            sv.z = fmaf(a.z, b.z, sv.z); sv.w = fmaf(a.w, b.w, sv.w);
        }
        float s = (sv.x + sv.y) + (sv.z + sv.w);
        s += __shfl_xor(s, 32, 64);                       // combine k-halves
        unsigned long long best = ((unsigned long long)mono_f32(s) << 32)
                                | (unsigned int)(65535 - col);
        #pragma unroll
        for (int off = 1; off <= 16; off <<= 1) {
            unsigned long long o = __shfl_xor(best, off, 64);
            best = best > o ? best : o;
        }
        if (lane == 0) atomicMax(rowfinal + row, best);
    }
}

// ---------------- k3: S1/S2 similarity matrices (8 rows x 256-col half per block) --------
__global__ void k3_sim(const unsigned long long* __restrict__ rowfinal,
                       const float* __restrict__ queue,
                       const float* __restrict__ PnT, float* __restrict__ S)
{
    const int b  = blockIdx.x;       // 0..255
    const int rb = (b >> 1) * 8;     // 0..1016 (rows of [nn1;nn2])
    const int ch = b & 1;            // column half
    const int tid = threadIdx.x;     // 256
    const int which = (rb < BATCH) ? 0 : 1;
    const int colbase = which ? 0 : BATCH;    // S1 vs p2 (cols 512..1023), S2 vs p1 (0..511)
    const int col = colbase + ch * 256 + tid;
    __shared__ float nnv[8][DIM];
    #pragma unroll
    for (int j = 0; j < 8; ++j) {
        const int idx = 65535 - (int)(rowfinal[rb + j] & 0xFFFFull);
        nnv[j][tid] = queue[(size_t)idx * DIM + tid];
    }
    __syncthreads();
    float acc[8];
    #pragma unroll
    for (int j = 0; j < 8; ++j) acc[j] = 0.f;
    for (int k4 = 0; k4 < 64; ++k4) {
        float4 nv[8];
        #pragma unroll
        for (int j = 0; j < 8; ++j) nv[j] = ((const float4*)nnv[j])[k4];
        #pragma unroll
        for (int kk = 0; kk < 4; ++kk) {
            const int k = k4 * 4 + kk;
            const float v0 = PnT[(size_t)k * MROWS + col];
            #pragma unroll
            for (int j = 0; j < 8; ++j) {
                const float nj = ((const float*)&nv[j])[kk];
                acc[j] = fmaf(nj, v0, acc[j]);
            }
        }
    }
    const int i0 = rb & (BATCH - 1);
    float* Sout = S + (size_t)which * (BATCH * BATCH);
    #pragma unroll
    for (int j = 0; j < 8; ++j)
        Sout[(size_t)(i0 + j) * BATCH + ch * 256 + tid] = acc[j] * 10.0f;
}

// ---------------- k4: loss ----------------
__global__ void k4_loss(const float* __restrict__ S, float* __restrict__ loss)
{
    const int r = blockIdx.x;        // 0..2047
    const int tid = threadIdx.x;     // 256
    const int grp = r >> 9;
    const int i = r & 511;
    const float* M = S + (size_t)(grp >> 1) * (BATCH * BATCH);
    float x0, x1;
    if (!(grp & 1)) { x0 = M[(size_t)i * BATCH + tid];  x1 = M[(size_t)i * BATCH + tid + 256]; }
    else            { x0 = M[(size_t)tid * BATCH + i];  x1 = M[(size_t)(tid + 256) * BATCH + i]; }
    const float diag = M[(size_t)i * BATCH + i];
    float mx = fmaxf(x0, x1);
    #pragma unroll
    for (int off = 1; off < 64; off <<= 1) mx = fmaxf(mx, __shfl_xor(mx, off, 64));
    __shared__ float redm[4], reds[4];
    if ((tid & 63) == 0) redm[tid >> 6] = mx;
    __syncthreads();
    mx = fmaxf(fmaxf(redm[0], redm[1]), fmaxf(redm[2], redm[3]));
    float e = __expf(x0 - mx) + __expf(x1 - mx);
    #pragma unroll
    for (int off = 1; off < 64; off <<= 1) e += __shfl_xor(e, off, 64);
    if ((tid & 63) == 0) reds[tid >> 6] = e;
    __syncthreads();
    if (tid == 0)
        loss[r] = mx + logf(reds[0] + reds[1] + reds[2] + reds[3]) - diag;
}

// ---------------- launcher ----------------
extern "C" void kernel_launch(void* const* d_in, const int* in_sizes, int n_in,
                              void* d_out, int out_size, void* d_ws, size_t ws_size,
                              hipStream_t stream)
{
    const float* p1    = (const float*)d_in[0];
    const float* p2    = (const float*)d_in[1];
    const float* queue = (const float*)d_in[2];
    float* out  = (float*)d_out;
    float* loss = out;
    float* outq = out + 4 * BATCH;

    // Workspace (~44.5 MB). Qbf (32 MB) aliases pairs: Qbf dead after k2, pairs born in k2c.
    char* w = (char*)d_ws;
    float* cand = (float*)w;                               w += (size_t)NGRP * MROWS * 4;   // 8 MB [g][m]
    unsigned long long* rowfinal = (unsigned long long*)w; w += MROWS * 8;
    unsigned int* rowmaxU = (unsigned int*)w;              w += MROWS * 4;
    float* Pn  = (float*)w;                                w += (size_t)MROWS * DIM * 4;    // 1 MB
    float* PnT = (float*)w;                                w += (size_t)MROWS * DIM * 4;    // 1 MB
    unsigned short* PhiF = (unsigned short*)w;             w += (size_t)MROWS * DIM * 2;    // 0.5 MB
    float* S = (float*)w;                                  w += (size_t)2 * BATCH * BATCH * 4; // 2 MB
    int* npairs = (int*)w;                                 w += 16;
    char* Qbf = w;                                         // 32 MB (QUEUE*DIM*2)
    unsigned int* pairs = (unsigned int*)Qbf;              // alias (see above)

    hipLaunchKernelGGL(k1_norm,     dim3(MROWS), dim3(64),  0, stream, p1, p2, Pn, PnT, PhiF, outq,
                       npairs, rowmaxU, rowfinal);
    hipLaunchKernelGGL(k0_prep,     dim3(QUEUE / 32), dim3(256), 0, stream, queue, outq, Qbf);
    hipLaunchKernelGGL(k2_mfma,     dim3(1024), dim3(256), 0, stream, PhiF, Qbf, cand, rowmaxU);
    hipLaunchKernelGGL(k2c_filter,  dim3(256),   dim3(256), 0, stream, cand, rowmaxU, pairs, npairs);
    hipLaunchKernelGGL(k2d_rescore, dim3(512),   dim3(256), 0, stream, pairs, npairs, Pn, queue, rowfinal);
    hipLaunchKernelGGL(k3_sim,      dim3(256),   dim3(256), 0, stream, rowfinal, queue, PnT, S);
    hipLaunchKernelGGL(k4_loss,     dim3(4 * BATCH), dim3(256), 0, stream, S, loss);
}

// Round 7
// 213.658 us; speedup vs baseline: 1.2439x; 1.0875x over previous
//
#include <hip/hip_runtime.h>
#include <stdint.h>

// NNCLR forward on MI355X — round 12.
// Changes vs round 11 (232.3 us; all own kernels now < fill's 40 us):
//  * k01_prep: k1 fused into k0 as heterogeneous grid (blocks 0..2047 k0-slabs,
//    2048..2303 k1-rows x4). k1's ~5 us hides under k0's BW stream; -1 launch.
//  * k2cd: k2c filter + k2d rescore fused. Per-block LDS hit list (cap 8192 = per-block
//    theoretical max), waves rescore in place. Deletes pairs buffer + npairs; -1 launch.
//  * k3_sim: 256 -> 512 blocks (4 rows/block) — serial k-loop halved, 2 blocks/CU.
//  * k0 path / k2_mfma untouched (near floor; k2 XCD remap + fused rowmax kept).

#define BATCH  512
#define DIM    256
#define QUEUE  65536
#define MROWS  1024
#define NGRP   2048          // 65536 / 32
#define MARGIN 0.01f

typedef short bf16x8 __attribute__((ext_vector_type(8)));
typedef float f32x4  __attribute__((ext_vector_type(4)));

__device__ __forceinline__ unsigned int mono_f32(float f) {
    unsigned int u = __float_as_uint(f);
    return (u & 0x80000000u) ? ~u : (u | 0x80000000u);
}
__device__ __forceinline__ float unmono_f32(unsigned int m) {
    unsigned int u = (m & 0x80000000u) ? (m ^ 0x80000000u) : ~m;
    return __uint_as_float(u);
}
__device__ __forceinline__ unsigned short f2bf(float f) {   // RNE fp32->bf16
    unsigned int u = __float_as_uint(f);
    return (unsigned short)((u + 0x7fffu + ((u >> 16) & 1u)) >> 16);
}

// ---------------- k01: (blocks 0..2047) queue->outq copy + Qbf  |  (2048..2303) normalize --
// k0 part: 32-row slab per block. Phase 1: 8 f32x4 loads; phase 2: plain outq stores +
// one 16B Qbf store per 32B chunk. Qbf tile (b>>1) at byte (b>>1)*32768; 16B chunk
// (rr,c16) at rr*512 + ((c16^(rr&31))<<4) — the LDS image k2 reads.
// k1 part: 4 rows/block (one per wave). PhiF 16B-chunk idx for (row r, k-chunk c):
// ((r>>4)*8 + (c>>2))*64 + (c&3)*16 + (r&15) -> k2 preload is coalesced b128.
__global__ __launch_bounds__(256)
void k01_prep(const float* __restrict__ queue, float* __restrict__ outq,
              char* __restrict__ Qbf,
              const float* __restrict__ p1, const float* __restrict__ p2,
              float* __restrict__ Pn, float* __restrict__ PnT,
              unsigned short* __restrict__ PhiF,
              unsigned int* __restrict__ rowmaxU, unsigned long long* __restrict__ rowfinal)
{
    const int bid = blockIdx.x;
    const int t = threadIdx.x;       // 0..255

    if (bid < 2048) {
        // ---------- k0: FIFO copy + Qbf ----------
        const int n0 = bid * 32;
        const f32x4* qsrc = (const f32x4*)(queue + (size_t)n0 * DIM);
        f32x4* qdst = (f32x4*)(outq + (size_t)(n0 + BATCH) * DIM);
        char* tile = Qbf + (size_t)(bid >> 1) * 32768;

        f32x4 va[8];
        #pragma unroll
        for (int it = 0; it < 4; ++it) {
            const int L = it * 256 + t;          // 0..1023: 32B chunk id
            const int r = L >> 5, c16 = L & 31;
            va[2 * it]     = qsrc[(size_t)r * 64 + c16 * 2];
            va[2 * it + 1] = qsrc[(size_t)r * 64 + c16 * 2 + 1];
        }
        #pragma unroll
        for (int it = 0; it < 4; ++it) {
            const int L = it * 256 + t;
            const int r = L >> 5, c16 = L & 31;
            f32x4 v0 = va[2 * it], v1 = va[2 * it + 1];
            if (n0 + r < QUEUE - BATCH) {
                qdst[(size_t)r * 64 + c16 * 2]     = v0;
                qdst[(size_t)r * 64 + c16 * 2 + 1] = v1;
            }
            bf16x8 bb;
            bb[0] = (short)f2bf(v0.x); bb[1] = (short)f2bf(v0.y);
            bb[2] = (short)f2bf(v0.z); bb[3] = (short)f2bf(v0.w);
            bb[4] = (short)f2bf(v1.x); bb[5] = (short)f2bf(v1.y);
            bb[6] = (short)f2bf(v1.z); bb[7] = (short)f2bf(v1.w);
            const int rr = ((bid & 1) << 5) + r;   // row within 64-row tile
            *(bf16x8*)(tile + rr * 512 + ((c16 ^ (rr & 31)) << 4)) = bb;
        }
    } else {
        // ---------- k1: normalize 4 rows (one per wave) ----------
        const int sub = t >> 6, lane = t & 63;
        const int r = (bid - 2048) * 4 + sub;    // 0..1023
        if (lane == 0) {                          // ws re-poisoned 0xAA each call
            rowmaxU[r] = 0u;
            rowfinal[r] = 0ull;
        }
        const float* src = (r < BATCH) ? p1 : p2;
        const int row = (r < BATCH) ? r : r - BATCH;
        float4 v = ((const float4*)(src + (size_t)row * DIM))[lane];
        float sq = v.x*v.x + v.y*v.y + v.z*v.z + v.w*v.w;
        #pragma unroll
        for (int off = 32; off; off >>= 1) sq += __shfl_xor(sq, off, 64);
        sq = fmaxf(sq, 1e-12f);
        float s = rsqrtf(sq);
        s = s * (1.5f - 0.5f * sq * s * s);
        v.x *= s; v.y *= s; v.z *= s; v.w *= s;
        ((float4*)(Pn + (size_t)r * DIM))[lane] = v;
        const int k = lane * 4;
        PnT[(size_t)(k + 0) * MROWS + r] = v.x;
        PnT[(size_t)(k + 1) * MROWS + r] = v.y;
        PnT[(size_t)(k + 2) * MROWS + r] = v.z;
        PnT[(size_t)(k + 3) * MROWS + r] = v.w;
        short4 b;
        b.x = (short)f2bf(v.x); b.y = (short)f2bf(v.y);
        b.z = (short)f2bf(v.z); b.w = (short)f2bf(v.w);
        {
            const int c = lane >> 1;
            const int idx = ((r >> 4) * 8 + (c >> 2)) * 64 + (c & 3) * 16 + (r & 15);
            *(short4*)((char*)PhiF + (size_t)idx * 16 + (lane & 1) * 8) = b;
        }
        if (r < BATCH) ((float4*)(outq + (size_t)r * DIM))[lane] = v;  // new_queue[0:512] = p1n
    }
}

// ---------------- k2: pure bf16 MFMA GEMM filter + fused rowmax ----------------
// Grid 1024; bid remap c=(bid>>5)*8+(bid&7), s=(bid>>3)&3 so the 4 strips sharing a
// Qbf chunk are bids {x,x+8,x+16,x+24} -> same XCD, adjacent dispatch -> L2 sharing.
// Block = 256 thr = 4 waves; wave w: m-rows [s*256 + w*64, +64), pfr[4][8] resident.
// Staging: global_load_lds 16B from pre-swizzled Qbf. Inner: 4 ds_read_b128 + 16 MFMA
// per ks. C rows = n (q*4+reg), cols = m (lr). Epilogue accumulates per-m rowmax and
// atomicMax's rowmaxU once per m per block.
__device__ __forceinline__ void k2_stage_async(const char* __restrict__ tile,
                                               char* Bsb, int t)
{
    #pragma unroll
    for (int it = 0; it < 8; ++it) {
        const int L = it * 256 + t;          // 0..2047 chunks of 16B
        __builtin_amdgcn_global_load_lds(
            (const __attribute__((address_space(1))) unsigned int*)(tile + (size_t)L * 16),
            (__attribute__((address_space(3))) unsigned int*)(Bsb + L * 16), 16, 0, 0);
    }
}

__global__ __launch_bounds__(256, 2)
void k2_mfma(const unsigned short* __restrict__ PhiF, const char* __restrict__ Qbf,
             float* __restrict__ cand, unsigned int* __restrict__ rowmaxU)
{
    __shared__ __align__(16) char Bs[2][32768];
    const int bid = blockIdx.x;      // 0..1023
    const int c = (bid >> 5) * 8 + (bid & 7);   // n-chunk 0..255
    const int s = (bid >> 3) & 3;               // m-strip 0..3
    const int t  = threadIdx.x;
    const int w  = t >> 6, lane = t & 63;
    const int lr = lane & 15, q = lane >> 4;
    const int mbase = s * 256 + w * 64;
    const char* chunkbase = Qbf + (size_t)(c * 4) * 32768;

    // ---- preload P fragments: 64 m-rows x K=256 resident; coalesced from PhiF
    bf16x8 pfr[4][8];
    {
        const char* Pw = (const char*)PhiF;
        const int mt16b = mbase >> 4;        // base 16-row tile index
        #pragma unroll
        for (int mj = 0; mj < 4; ++mj)
            #pragma unroll
            for (int ks = 0; ks < 8; ++ks)
                pfr[mj][ks] = *(const bf16x8*)(Pw + ((size_t)((mt16b + mj) * 8 + ks) * 64 + lane) * 16);
    }

    k2_stage_async(chunkbase, Bs[0], t);
    __syncthreads();

    float rowmx[4] = {-1e30f, -1e30f, -1e30f, -1e30f};

    for (int tl = 0; tl < 4; ++tl) {
        if (tl < 3)
            k2_stage_async(chunkbase + (size_t)(tl + 1) * 32768, Bs[(tl + 1) & 1], t);

        char* Bsb = Bs[tl & 1];
        f32x4 acc[4][4];                 // [ni][mj]
        #pragma unroll
        for (int i = 0; i < 4; ++i)
            #pragma unroll
            for (int j = 0; j < 4; ++j) acc[i][j] = (f32x4){0.f, 0.f, 0.f, 0.f};

        #pragma unroll
        for (int ks = 0; ks < 8; ++ks) {
            bf16x8 qf[4];
            #pragma unroll
            for (int ni = 0; ni < 4; ++ni) {
                const int r = ni * 16 + lr;
                const int c16 = ks * 4 + q;
                qf[ni] = *(const bf16x8*)(Bsb + r * 512 + ((c16 ^ (r & 31)) << 4));
            }
            #pragma unroll
            for (int ni = 0; ni < 4; ++ni)
                #pragma unroll
                for (int mj = 0; mj < 4; ++mj)
                    acc[ni][mj] = __builtin_amdgcn_mfma_f32_16x16x32_bf16(qf[ni], pfr[mj][ks], acc[ni][mj], 0, 0, 0);
        }

        // ---- epilogue: per (m, 32-n-group) max. n in-lane (+q), m across 16 lanes.
        #pragma unroll
        for (int mj = 0; mj < 4; ++mj) {
            #pragma unroll
            for (int gl = 0; gl < 2; ++gl) {
                f32x4 va = acc[2 * gl][mj], vb = acc[2 * gl + 1][mj];
                float mx = fmaxf(fmaxf(fmaxf(va[0], va[1]), fmaxf(va[2], va[3])),
                                 fmaxf(fmaxf(vb[0], vb[1]), fmaxf(vb[2], vb[3])));
                mx = fmaxf(mx, __shfl_xor(mx, 16, 64));
                mx = fmaxf(mx, __shfl_xor(mx, 32, 64));
                rowmx[mj] = fmaxf(rowmx[mj], mx);
                if (q == 0)
                    cand[(size_t)(c * 8 + tl * 2 + gl) * MROWS + (mbase + mj * 16 + lr)] = mx;
            }
        }
        __syncthreads();
    }

    // ---- fused rowmax: one atomic per m per block
    if (q == 0) {
        #pragma unroll
        for (int mj = 0; mj < 4; ++mj)
            atomicMax(rowmaxU + mbase + mj * 16 + lr, mono_f32(rowmx[mj]));
    }
}

// ---------------- k2cd: margin filter -> LDS hit list -> exact fp32 rescore ----------------
// Grid 256 = 16 m-chunks x 16 g-chunks. Phase 1 (k2c): threads scan cand, push hits to
// LDS (cap 8192 = 64m x 128g, the per-block theoretical max). Phase 2 (k2d): the 4 waves
// rescore hits round-robin; one wave per (row,group): 32 cols x 256-dim fp32 dot,
// atomicMax(rowfinal). No global pair list.
__global__ __launch_bounds__(256)
void k2cd(const float* __restrict__ cand, const unsigned int* __restrict__ rowmaxU,
          const float* __restrict__ Pn, const float* __restrict__ queue,
          unsigned long long* __restrict__ rowfinal)
{
    __shared__ unsigned int hits[8192];
    __shared__ int nhits;
    const int t = threadIdx.x;               // 256
    if (t == 0) nhits = 0;
    __syncthreads();

    {   // ---- phase 1: filter
        const int ml = t & 63, gs = t >> 6;
        const int mc = blockIdx.x & 15, gc = blockIdx.x >> 4;
        const int m  = mc * 64 + ml;
        const int g0 = gc * 128 + gs * 32;
        const float thr = unmono_f32(rowmaxU[m]) - MARGIN;
        #pragma unroll 8
        for (int j = 0; j < 32; ++j) {
            if (cand[(size_t)(g0 + j) * MROWS + m] >= thr) {
                int p = atomicAdd(&nhits, 1);
                hits[p] = ((unsigned int)m << 16) | (unsigned int)(g0 + j);
            }
        }
    }
    __syncthreads();

    // ---- phase 2: rescore
    const int n = nhits;
    const int w = t >> 6, lane = t & 63;
    const int col_l = lane & 31, half = lane >> 5;
    for (int p = w; p < n; p += 4) {
        const unsigned int pr = hits[p];
        const int row = pr >> 16, g = pr & 0xffff;
        const int col = g * 32 + col_l;
        const float4* qp = (const float4*)(queue + (size_t)col * DIM + half * 128);
        const float4* pp = (const float4*)(Pn + (size_t)row * DIM + half * 128);
        float4 sv = {0.f, 0.f, 0.f, 0.f};
        #pragma unroll 8
        for (int j = 0; j < 32; ++j) {
            float4 a = pp[j], b = qp[j];
            sv.x = fmaf(a.x, b.x, sv.x); sv.y = fmaf(a.y, b.y, sv.y);
            sv.z = fmaf(a.z, b.z, sv.z); sv.w = fmaf(a.w, b.w, sv.w);
        }
        float s = (sv.x + sv.y) + (sv.z + sv.w);
        s += __shfl_xor(s, 32, 64);                       // combine k-halves
        unsigned long long best = ((unsigned long long)mono_f32(s) << 32)
                                | (unsigned int)(65535 - col);
        #pragma unroll
        for (int off = 1; off <= 16; off <<= 1) {
            unsigned long long o = __shfl_xor(best, off, 64);
            best = best > o ? best : o;
        }
        if (lane == 0) atomicMax(rowfinal + row, best);
    }
}

// ---------------- k3: S1/S2 similarity matrices (4 rows x 256-col half per block) --------
// grid 512: b>>1 = 4-row block (rows of [nn1;nn2]), b&1 = column half.
__global__ void k3_sim(const unsigned long long* __restrict__ rowfinal,
                       const float* __restrict__ queue,
                       const float* __restrict__ PnT, float* __restrict__ S)
{
    const int b  = blockIdx.x;       // 0..511
    const int rb = (b >> 1) * 4;     // 0..1020 (rows of [nn1;nn2])
    const int ch = b & 1;            // column half
    const int tid = threadIdx.x;     // 256
    const int which = (rb < BATCH) ? 0 : 1;
    const int colbase = which ? 0 : BATCH;    // S1 vs p2 (cols 512..1023), S2 vs p1 (0..511)
    const int col = colbase + ch * 256 + tid;
    __shared__ float nnv[4][DIM];
    #pragma unroll
    for (int j = 0; j < 4; ++j) {
        const int idx = 65535 - (int)(rowfinal[rb + j] & 0xFFFFull);
        nnv[j][tid] = queue[(size_t)idx * DIM + tid];
    }
    __syncthreads();
    float acc[4];
    #pragma unroll
    for (int j = 0; j < 4; ++j) acc[j] = 0.f;
    for (int k4 = 0; k4 < 64; ++k4) {
        float4 nv[4];
        #pragma unroll
        for (int j = 0; j < 4; ++j) nv[j] = ((const float4*)nnv[j])[k4];
        #pragma unroll
        for (int kk = 0; kk < 4; ++kk) {
            const int k = k4 * 4 + kk;
            const float v0 = PnT[(size_t)k * MROWS + col];
            #pragma unroll
            for (int j = 0; j < 4; ++j) {
                const float nj = ((const float*)&nv[j])[kk];
                acc[j] = fmaf(nj, v0, acc[j]);
            }
        }
    }
    const int i0 = rb & (BATCH - 1);
    float* Sout = S + (size_t)which * (BATCH * BATCH);
    #pragma unroll
    for (int j = 0; j < 4; ++j)
        Sout[(size_t)(i0 + j) * BATCH + ch * 256 + tid] = acc[j] * 10.0f;
}

// ---------------- k4: loss ----------------
__global__ void k4_loss(const float* __restrict__ S, float* __restrict__ loss)
{
    const int r = blockIdx.x;        // 0..2047
    const int tid = threadIdx.x;     // 256
    const int grp = r >> 9;
    const int i = r & 511;
    const float* M = S + (size_t)(grp >> 1) * (BATCH * BATCH);
    float x0, x1;
    if (!(grp & 1)) { x0 = M[(size_t)i * BATCH + tid];  x1 = M[(size_t)i * BATCH + tid + 256]; }
    else            { x0 = M[(size_t)tid * BATCH + i];  x1 = M[(size_t)(tid + 256) * BATCH + i]; }
    const float diag = M[(size_t)i * BATCH + i];
    float mx = fmaxf(x0, x1);
    #pragma unroll
    for (int off = 1; off < 64; off <<= 1) mx = fmaxf(mx, __shfl_xor(mx, off, 64));
    __shared__ float redm[4], reds[4];
    if ((tid & 63) == 0) redm[tid >> 6] = mx;
    __syncthreads();
    mx = fmaxf(fmaxf(redm[0], redm[1]), fmaxf(redm[2], redm[3]));
    float e = __expf(x0 - mx) + __expf(x1 - mx);
    #pragma unroll
    for (int off = 1; off < 64; off <<= 1) e += __shfl_xor(e, off, 64);
    if ((tid & 63) == 0) reds[tid >> 6] = e;
    __syncthreads();
    if (tid == 0)
        loss[r] = mx + logf(reds[0] + reds[1] + reds[2] + reds[3]) - diag;
}

// ---------------- launcher ----------------
extern "C" void kernel_launch(void* const* d_in, const int* in_sizes, int n_in,
                              void* d_out, int out_size, void* d_ws, size_t ws_size,
                              hipStream_t stream)
{
    const float* p1    = (const float*)d_in[0];
    const float* p2    = (const float*)d_in[1];
    const float* queue = (const float*)d_in[2];
    float* out  = (float*)d_out;
    float* loss = out;
    float* outq = out + 4 * BATCH;

    // Workspace (~44.5 MB; no pairs buffer anymore)
    char* w = (char*)d_ws;
    float* cand = (float*)w;                               w += (size_t)NGRP * MROWS * 4;   // 8 MB [g][m]
    unsigned long long* rowfinal = (unsigned long long*)w; w += MROWS * 8;
    unsigned int* rowmaxU = (unsigned int*)w;              w += MROWS * 4;
    float* Pn  = (float*)w;                                w += (size_t)MROWS * DIM * 4;    // 1 MB
    float* PnT = (float*)w;                                w += (size_t)MROWS * DIM * 4;    // 1 MB
    unsigned short* PhiF = (unsigned short*)w;             w += (size_t)MROWS * DIM * 2;    // 0.5 MB
    float* S = (float*)w;                                  w += (size_t)2 * BATCH * BATCH * 4; // 2 MB
    char* Qbf = w;                                         // 32 MB (QUEUE*DIM*2)

    hipLaunchKernelGGL(k01_prep,    dim3(2048 + 256), dim3(256), 0, stream,
                       queue, outq, Qbf, p1, p2, Pn, PnT, PhiF, rowmaxU, rowfinal);
    hipLaunchKernelGGL(k2_mfma,     dim3(1024), dim3(256), 0, stream, PhiF, Qbf, cand, rowmaxU);
    hipLaunchKernelGGL(k2cd,        dim3(256),  dim3(256), 0, stream, cand, rowmaxU, Pn, queue, rowfinal);
    hipLaunchKernelGGL(k3_sim,      dim3(512),  dim3(256), 0, stream, rowfinal, queue, PnT, S);
    hipLaunchKernelGGL(k4_loss,     dim3(4 * BATCH), dim3(256), 0, stream, S, loss);
}

// Round 8
// 213.400 us; speedup vs baseline: 1.2454x; 1.0012x over previous
//
#include <hip/hip_runtime.h>
#include <stdint.h>

// NNCLR forward on MI355X — round 13.
// Changes vs round 12 (213.7 us):
//  * k01_prep: k1-normalize blocks moved to FRONT of grid (bid 0..255). They were
//    trailing the 2048 k0 blocks (which exactly fill the machine at 8/CU), running
//    alone at the end with a slow strided PnT scatter -> tail. Now hidden under BW.
//  * k2_mfma: depth-2 counted-vmcnt pipeline (T3/T4 minimal form). 32-row half-tiles
//    (16KB), 4 LDS buffers (same 64KB total, 2 blocks/CU), raw s_barrier (no implicit
//    vmcnt(0) drain) + inline-asm s_waitcnt with exact FIFO counts (stores included).
//    Old structure exposed the full stage latency at every __syncthreads (vmcnt(0)
//    drain). acc [4][4]->[2][4] per half (-32 VGPR). cand group c*8+h == old layout.
//  * k2cd / k3 / k4 unchanged (passed, absmax 0).

#define BATCH  512
#define DIM    256
#define QUEUE  65536
#define MROWS  1024
#define NGRP   2048          // 65536 / 32
#define MARGIN 0.01f

typedef short bf16x8 __attribute__((ext_vector_type(8)));
typedef float f32x4  __attribute__((ext_vector_type(4)));

__device__ __forceinline__ unsigned int mono_f32(float f) {
    unsigned int u = __float_as_uint(f);
    return (u & 0x80000000u) ? ~u : (u | 0x80000000u);
}
__device__ __forceinline__ float unmono_f32(unsigned int m) {
    unsigned int u = (m & 0x80000000u) ? (m ^ 0x80000000u) : ~m;
    return __uint_as_float(u);
}
__device__ __forceinline__ unsigned short f2bf(float f) {   // RNE fp32->bf16
    unsigned int u = __float_as_uint(f);
    return (unsigned short)((u + 0x7fffu + ((u >> 16) & 1u)) >> 16);
}

// ---------------- k01: (blocks 0..255) normalize | (256..2303) queue->outq + Qbf ----------
// k1 part first so its slow PnT scatter hides under the k0 BW stream instead of tailing.
// k0 part: 32-row slab per block. Phase 1: 8 f32x4 loads; phase 2: plain outq stores +
// one 16B Qbf store per 32B chunk. Qbf tile at byte tile_idx*32768; 16B chunk (rr,c16)
// at rr*512 + ((c16^(rr&31))<<4) — the LDS image k2 reads.
// PhiF 16B-chunk idx for (row r, k-chunk c): ((r>>4)*8 + (c>>2))*64 + (c&3)*16 + (r&15).
__global__ __launch_bounds__(256)
void k01_prep(const float* __restrict__ queue, float* __restrict__ outq,
              char* __restrict__ Qbf,
              const float* __restrict__ p1, const float* __restrict__ p2,
              float* __restrict__ Pn, float* __restrict__ PnT,
              unsigned short* __restrict__ PhiF,
              unsigned int* __restrict__ rowmaxU, unsigned long long* __restrict__ rowfinal)
{
    const int bid = blockIdx.x;
    const int t = threadIdx.x;       // 0..255

    if (bid >= 256) {
        // ---------- k0: FIFO copy + Qbf ----------
        const int b0 = bid - 256;               // 0..2047
        const int n0 = b0 * 32;
        const f32x4* qsrc = (const f32x4*)(queue + (size_t)n0 * DIM);
        f32x4* qdst = (f32x4*)(outq + (size_t)(n0 + BATCH) * DIM);
        char* tile = Qbf + (size_t)(b0 >> 1) * 32768;

        f32x4 va[8];
        #pragma unroll
        for (int it = 0; it < 4; ++it) {
            const int L = it * 256 + t;          // 0..1023: 32B chunk id
            const int r = L >> 5, c16 = L & 31;
            va[2 * it]     = qsrc[(size_t)r * 64 + c16 * 2];
            va[2 * it + 1] = qsrc[(size_t)r * 64 + c16 * 2 + 1];
        }
        #pragma unroll
        for (int it = 0; it < 4; ++it) {
            const int L = it * 256 + t;
            const int r = L >> 5, c16 = L & 31;
            f32x4 v0 = va[2 * it], v1 = va[2 * it + 1];
            if (n0 + r < QUEUE - BATCH) {
                qdst[(size_t)r * 64 + c16 * 2]     = v0;
                qdst[(size_t)r * 64 + c16 * 2 + 1] = v1;
            }
            bf16x8 bb;
            bb[0] = (short)f2bf(v0.x); bb[1] = (short)f2bf(v0.y);
            bb[2] = (short)f2bf(v0.z); bb[3] = (short)f2bf(v0.w);
            bb[4] = (short)f2bf(v1.x); bb[5] = (short)f2bf(v1.y);
            bb[6] = (short)f2bf(v1.z); bb[7] = (short)f2bf(v1.w);
            const int rr = ((b0 & 1) << 5) + r;   // row within 64-row tile
            *(bf16x8*)(tile + rr * 512 + ((c16 ^ (rr & 31)) << 4)) = bb;
        }
    } else {
        // ---------- k1: normalize 4 rows (one per wave) ----------
        const int sub = t >> 6, lane = t & 63;
        const int r = bid * 4 + sub;             // 0..1023
        if (lane == 0) {                          // ws re-poisoned 0xAA each call
            rowmaxU[r] = 0u;
            rowfinal[r] = 0ull;
        }
        const float* src = (r < BATCH) ? p1 : p2;
        const int row = (r < BATCH) ? r : r - BATCH;
        float4 v = ((const float4*)(src + (size_t)row * DIM))[lane];
        float sq = v.x*v.x + v.y*v.y + v.z*v.z + v.w*v.w;
        #pragma unroll
        for (int off = 32; off; off >>= 1) sq += __shfl_xor(sq, off, 64);
        sq = fmaxf(sq, 1e-12f);
        float s = rsqrtf(sq);
        s = s * (1.5f - 0.5f * sq * s * s);
        v.x *= s; v.y *= s; v.z *= s; v.w *= s;
        ((float4*)(Pn + (size_t)r * DIM))[lane] = v;
        const int k = lane * 4;
        PnT[(size_t)(k + 0) * MROWS + r] = v.x;
        PnT[(size_t)(k + 1) * MROWS + r] = v.y;
        PnT[(size_t)(k + 2) * MROWS + r] = v.z;
        PnT[(size_t)(k + 3) * MROWS + r] = v.w;
        short4 b;
        b.x = (short)f2bf(v.x); b.y = (short)f2bf(v.y);
        b.z = (short)f2bf(v.z); b.w = (short)f2bf(v.w);
        {
            const int c = lane >> 1;
            const int idx = ((r >> 4) * 8 + (c >> 2)) * 64 + (c & 3) * 16 + (r & 15);
            *(short4*)((char*)PhiF + (size_t)idx * 16 + (lane & 1) * 8) = b;
        }
        if (r < BATCH) ((float4*)(outq + (size_t)r * DIM))[lane] = v;  // new_queue[0:512] = p1n
    }
}

// ---------------- k2: bf16 MFMA GEMM filter, depth-2 counted-vmcnt pipeline ----------------
// Grid 1024; bid remap c=(bid>>5)*8+(bid&7), s=(bid>>3)&3 (XCD sharing of Qbf chunks).
// Block = 256 thr = 4 waves; wave w: m-rows [s*256 + w*64, +64), pfr[4][8] resident.
// 8 half-tiles of 32 rows (16KB) per chunk, 4 LDS buffers. Per half h:
//   issue stage(h+2) -> s_waitcnt vmcnt(N) [FIFO-exact] -> s_barrier -> 16 ds_read +
//   64 MFMA + epilogue (4 cand stores) -> s_barrier.
// vmcnt N: h=0:8 [s1,s2]; h=1..5:12 [stores(h-1),s(h+1),s(h+2)]; h=6:8; h=7:4.
__device__ __forceinline__ void k2_stage_half(const char* __restrict__ src,
                                              char* dst, int t)
{
    #pragma unroll
    for (int it = 0; it < 4; ++it) {
        const int L = it * 256 + t;          // 0..1023 chunks of 16B
        __builtin_amdgcn_global_load_lds(
            (const __attribute__((address_space(1))) unsigned int*)(src + (size_t)L * 16),
            (__attribute__((address_space(3))) unsigned int*)(dst + L * 16), 16, 0, 0);
    }
}

__global__ __launch_bounds__(256, 2)
void k2_mfma(const unsigned short* __restrict__ PhiF, const char* __restrict__ Qbf,
             float* __restrict__ cand, unsigned int* __restrict__ rowmaxU)
{
    __shared__ __align__(16) char Bs[4][16384];
    const int bid = blockIdx.x;      // 0..1023
    const int c = (bid >> 5) * 8 + (bid & 7);   // n-chunk 0..255
    const int s = (bid >> 3) & 3;               // m-strip 0..3
    const int t  = threadIdx.x;
    const int w  = t >> 6, lane = t & 63;
    const int lr = lane & 15, q = lane >> 4;
    const int mbase = s * 256 + w * 64;
    const char* chunkbase = Qbf + (size_t)(c * 4) * 32768;   // 8 halves x 16KB

    // ---- preload P fragments: 64 m-rows x K=256 resident; coalesced from PhiF
    bf16x8 pfr[4][8];
    {
        const char* Pw = (const char*)PhiF;
        const int mt16b = mbase >> 4;        // base 16-row tile index
        #pragma unroll
        for (int mj = 0; mj < 4; ++mj)
            #pragma unroll
            for (int ks = 0; ks < 8; ++ks)
                pfr[mj][ks] = *(const bf16x8*)(Pw + ((size_t)((mt16b + mj) * 8 + ks) * 64 + lane) * 16);
    }

    k2_stage_half(chunkbase,         Bs[0], t);
    k2_stage_half(chunkbase + 16384, Bs[1], t);

    float rowmx[4] = {-1e30f, -1e30f, -1e30f, -1e30f};

    #pragma unroll
    for (int h = 0; h < 8; ++h) {
        if (h + 2 < 8)
            k2_stage_half(chunkbase + (size_t)(h + 2) * 16384, Bs[(h + 2) & 3], t);

        // FIFO-exact wait: everything up through stage(h) drained.
        if (h == 0)      asm volatile("s_waitcnt vmcnt(8)"  ::: "memory");
        else if (h <= 5) asm volatile("s_waitcnt vmcnt(12)" ::: "memory");
        else if (h == 6) asm volatile("s_waitcnt vmcnt(8)"  ::: "memory");
        else             asm volatile("s_waitcnt vmcnt(4)"  ::: "memory");
        __builtin_amdgcn_s_barrier();
        __builtin_amdgcn_sched_barrier(0);

        const char* Bsb = Bs[h & 3];
        f32x4 acc[2][4];                 // [ni][mj]
        #pragma unroll
        for (int i = 0; i < 2; ++i)
            #pragma unroll
            for (int j = 0; j < 4; ++j) acc[i][j] = (f32x4){0.f, 0.f, 0.f, 0.f};

        #pragma unroll
        for (int ks = 0; ks < 8; ++ks) {
            bf16x8 qf[2];
            #pragma unroll
            for (int ni = 0; ni < 2; ++ni) {
                const int rl = ni * 16 + lr;            // local row 0..31
                const int c16 = ks * 4 + q;
                qf[ni] = *(const bf16x8*)(Bsb + rl * 512 + ((c16 ^ rl) << 4));
            }
            #pragma unroll
            for (int ni = 0; ni < 2; ++ni)
                #pragma unroll
                for (int mj = 0; mj < 4; ++mj)
                    acc[ni][mj] = __builtin_amdgcn_mfma_f32_16x16x32_bf16(qf[ni], pfr[mj][ks], acc[ni][mj], 0, 0, 0);
        }

        // ---- epilogue: per (m, 32-n-group) max; group = c*8 + h (== old c*8+tl*2+gl).
        #pragma unroll
        for (int mj = 0; mj < 4; ++mj) {
            f32x4 va = acc[0][mj], vb = acc[1][mj];
            float mx = fmaxf(fmaxf(fmaxf(va[0], va[1]), fmaxf(va[2], va[3])),
                             fmaxf(fmaxf(vb[0], vb[1]), fmaxf(vb[2], vb[3])));
            mx = fmaxf(mx, __shfl_xor(mx, 16, 64));
            mx = fmaxf(mx, __shfl_xor(mx, 32, 64));
            rowmx[mj] = fmaxf(rowmx[mj], mx);
            if (q == 0)
                cand[(size_t)(c * 8 + h) * MROWS + (mbase + mj * 16 + lr)] = mx;
        }
        __builtin_amdgcn_s_barrier();
        __builtin_amdgcn_sched_barrier(0);
    }

    // ---- fused rowmax: one atomic per m per block
    if (q == 0) {
        #pragma unroll
        for (int mj = 0; mj < 4; ++mj)
            atomicMax(rowmaxU + mbase + mj * 16 + lr, mono_f32(rowmx[mj]));
    }
}

// ---------------- k2cd: margin filter -> LDS hit list -> exact fp32 rescore ----------------
// Grid 256 = 16 m-chunks x 16 g-chunks. Phase 1: scan cand, push hits to LDS (cap 8192 =
// per-block theoretical max). Phase 2: waves rescore hits round-robin; one wave per
// (row,group): 32 cols x 256-dim fp32 dot, atomicMax(rowfinal).
__global__ __launch_bounds__(256)
void k2cd(const float* __restrict__ cand, const unsigned int* __restrict__ rowmaxU,
          const float* __restrict__ Pn, const float* __restrict__ queue,
          unsigned long long* __restrict__ rowfinal)
{
    __shared__ unsigned int hits[8192];
    __shared__ int nhits;
    const int t = threadIdx.x;               // 256
    if (t == 0) nhits = 0;
    __syncthreads();

    {   // ---- phase 1: filter
        const int ml = t & 63, gs = t >> 6;
        const int mc = blockIdx.x & 15, gc = blockIdx.x >> 4;
        const int m  = mc * 64 + ml;
        const int g0 = gc * 128 + gs * 32;
        const float thr = unmono_f32(rowmaxU[m]) - MARGIN;
        #pragma unroll 8
        for (int j = 0; j < 32; ++j) {
            if (cand[(size_t)(g0 + j) * MROWS + m] >= thr) {
                int p = atomicAdd(&nhits, 1);
                hits[p] = ((unsigned int)m << 16) | (unsigned int)(g0 + j);
            }
        }
    }
    __syncthreads();

    // ---- phase 2: rescore
    const int n = nhits;
    const int w = t >> 6, lane = t & 63;
    const int col_l = lane & 31, half = lane >> 5;
    for (int p = w; p < n; p += 4) {
        const unsigned int pr = hits[p];
        const int row = pr >> 16, g = pr & 0xffff;
        const int col = g * 32 + col_l;
        const float4* qp = (const float4*)(queue + (size_t)col * DIM + half * 128);
        const float4* pp = (const float4*)(Pn + (size_t)row * DIM + half * 128);
        float4 sv = {0.f, 0.f, 0.f, 0.f};
        #pragma unroll 8
        for (int j = 0; j < 32; ++j) {
            float4 a = pp[j], b = qp[j];
            sv.x = fmaf(a.x, b.x, sv.x); sv.y = fmaf(a.y, b.y, sv.y);
            sv.z = fmaf(a.z, b.z, sv.z); sv.w = fmaf(a.w, b.w, sv.w);
        }
        float s = (sv.x + sv.y) + (sv.z + sv.w);
        s += __shfl_xor(s, 32, 64);                       // combine k-halves
        unsigned long long best = ((unsigned long long)mono_f32(s) << 32)
                                | (unsigned int)(65535 - col);
        #pragma unroll
        for (int off = 1; off <= 16; off <<= 1) {
            unsigned long long o = __shfl_xor(best, off, 64);
            best = best > o ? best : o;
        }
        if (lane == 0) atomicMax(rowfinal + row, best);
    }
}

// ---------------- k3: S1/S2 similarity matrices (4 rows x 256-col half per block) --------
// grid 512: b>>1 = 4-row block (rows of [nn1;nn2]), b&1 = column half.
__global__ void k3_sim(const unsigned long long* __restrict__ rowfinal,
                       const float* __restrict__ queue,
                       const float* __restrict__ PnT, float* __restrict__ S)
{
    const int b  = blockIdx.x;       // 0..511
    const int rb = (b >> 1) * 4;     // 0..1020 (rows of [nn1;nn2])
    const int ch = b & 1;            // column half
    const int tid = threadIdx.x;     // 256
    const int which = (rb < BATCH) ? 0 : 1;
    const int colbase = which ? 0 : BATCH;    // S1 vs p2 (cols 512..1023), S2 vs p1 (0..511)
    const int col = colbase + ch * 256 + tid;
    __shared__ float nnv[4][DIM];
    #pragma unroll
    for (int j = 0; j < 4; ++j) {
        const int idx = 65535 - (int)(rowfinal[rb + j] & 0xFFFFull);
        nnv[j][tid] = queue[(size_t)idx * DIM + tid];
    }
    __syncthreads();
    float acc[4];
    #pragma unroll
    for (int j = 0; j < 4; ++j) acc[j] = 0.f;
    for (int k4 = 0; k4 < 64; ++k4) {
        float4 nv[4];
        #pragma unroll
        for (int j = 0; j < 4; ++j) nv[j] = ((const float4*)nnv[j])[k4];
        #pragma unroll
        for (int kk = 0; kk < 4; ++kk) {
            const int k = k4 * 4 + kk;
            const float v0 = PnT[(size_t)k * MROWS + col];
            #pragma unroll
            for (int j = 0; j < 4; ++j) {
                const float nj = ((const float*)&nv[j])[kk];
                acc[j] = fmaf(nj, v0, acc[j]);
            }
        }
    }
    const int i0 = rb & (BATCH - 1);
    float* Sout = S + (size_t)which * (BATCH * BATCH);
    #pragma unroll
    for (int j = 0; j < 4; ++j)
        Sout[(size_t)(i0 + j) * BATCH + ch * 256 + tid] = acc[j] * 10.0f;
}

// ---------------- k4: loss ----------------
__global__ void k4_loss(const float* __restrict__ S, float* __restrict__ loss)
{
    const int r = blockIdx.x;        // 0..2047
    const int tid = threadIdx.x;     // 256
    const int grp = r >> 9;
    const int i = r & 511;
    const float* M = S + (size_t)(grp >> 1) * (BATCH * BATCH);
    float x0, x1;
    if (!(grp & 1)) { x0 = M[(size_t)i * BATCH + tid];  x1 = M[(size_t)i * BATCH + tid + 256]; }
    else            { x0 = M[(size_t)tid * BATCH + i];  x1 = M[(size_t)(tid + 256) * BATCH + i]; }
    const float diag = M[(size_t)i * BATCH + i];
    float mx = fmaxf(x0, x1);
    #pragma unroll
    for (int off = 1; off < 64; off <<= 1) mx = fmaxf(mx, __shfl_xor(mx, off, 64));
    __shared__ float redm[4], reds[4];
    if ((tid & 63) == 0) redm[tid >> 6] = mx;
    __syncthreads();
    mx = fmaxf(fmaxf(redm[0], redm[1]), fmaxf(redm[2], redm[3]));
    float e = __expf(x0 - mx) + __expf(x1 - mx);
    #pragma unroll
    for (int off = 1; off < 64; off <<= 1) e += __shfl_xor(e, off, 64);
    if ((tid & 63) == 0) reds[tid >> 6] = e;
    __syncthreads();
    if (tid == 0)
        loss[r] = mx + logf(reds[0] + reds[1] + reds[2] + reds[3]) - diag;
}

// ---------------- launcher ----------------
extern "C" void kernel_launch(void* const* d_in, const int* in_sizes, int n_in,
                              void* d_out, int out_size, void* d_ws, size_t ws_size,
                              hipStream_t stream)
{
    const float* p1    = (const float*)d_in[0];
    const float* p2    = (const float*)d_in[1];
    const float* queue = (const float*)d_in[2];
    float* out  = (float*)d_out;
    float* loss = out;
    float* outq = out + 4 * BATCH;

    // Workspace (~44.5 MB)
    char* w = (char*)d_ws;
    float* cand = (float*)w;                               w += (size_t)NGRP * MROWS * 4;   // 8 MB [g][m]
    unsigned long long* rowfinal = (unsigned long long*)w; w += MROWS * 8;
    unsigned int* rowmaxU = (unsigned int*)w;              w += MROWS * 4;
    float* Pn  = (float*)w;                                w += (size_t)MROWS * DIM * 4;    // 1 MB
    float* PnT = (float*)w;                                w += (size_t)MROWS * DIM * 4;    // 1 MB
    unsigned short* PhiF = (unsigned short*)w;             w += (size_t)MROWS * DIM * 2;    // 0.5 MB
    float* S = (float*)w;                                  w += (size_t)2 * BATCH * BATCH * 4; // 2 MB
    char* Qbf = w;                                         // 32 MB (QUEUE*DIM*2)

    hipLaunchKernelGGL(k01_prep,    dim3(256 + 2048), dim3(256), 0, stream,
                       queue, outq, Qbf, p1, p2, Pn, PnT, PhiF, rowmaxU, rowfinal);
    hipLaunchKernelGGL(k2_mfma,     dim3(1024), dim3(256), 0, stream, PhiF, Qbf, cand, rowmaxU);
    hipLaunchKernelGGL(k2cd,        dim3(256),  dim3(256), 0, stream, cand, rowmaxU, Pn, queue, rowfinal);
    hipLaunchKernelGGL(k3_sim,      dim3(512),  dim3(256), 0, stream, rowfinal, queue, PnT, S);
    hipLaunchKernelGGL(k4_loss,     dim3(4 * BATCH), dim3(256), 0, stream, S, loss);
}

// Round 9
// 212.940 us; speedup vs baseline: 1.2481x; 1.0022x over previous
//
#include <hip/hip_runtime.h>
#include <stdint.h>

// NNCLR forward on MI355X — round 14.
// Changes vs round 13 (213.4 us; both r13 changes neutral, kept):
//  * k01_prep (k0 part): __builtin_amdgcn_sched_barrier(0) between the 8-load phase and
//    the store phase. r13 counters: VGPR_Count=24 -> compiler sank loads into the store
//    loop (~1-2 in flight), MLP-starved at 3.3 TB/s vs 6.6 fill ceiling. Pinning issue
//    order keeps 8 loads/thread outstanding (~128 KB/CU in flight vs ~21 KB needed).
//  * k2cd: grid 256 -> 512 (16 m-chunks x 32 g-chunks, 64 g each) — halves the serial
//    per-block rescore chain in phase 2. Phase-1 traffic unchanged.
//  * k2_mfma (r13 counted-vmcnt pipeline) / k3 / k4 unchanged (passed, absmax 0).

#define BATCH  512
#define DIM    256
#define QUEUE  65536
#define MROWS  1024
#define NGRP   2048          // 65536 / 32
#define MARGIN 0.01f

typedef short bf16x8 __attribute__((ext_vector_type(8)));
typedef float f32x4  __attribute__((ext_vector_type(4)));

__device__ __forceinline__ unsigned int mono_f32(float f) {
    unsigned int u = __float_as_uint(f);
    return (u & 0x80000000u) ? ~u : (u | 0x80000000u);
}
__device__ __forceinline__ float unmono_f32(unsigned int m) {
    unsigned int u = (m & 0x80000000u) ? (m ^ 0x80000000u) : ~m;
    return __uint_as_float(u);
}
__device__ __forceinline__ unsigned short f2bf(float f) {   // RNE fp32->bf16
    unsigned int u = __float_as_uint(f);
    return (unsigned short)((u + 0x7fffu + ((u >> 16) & 1u)) >> 16);
}

// ---------------- k01: (blocks 0..255) normalize | (256..2303) queue->outq + Qbf ----------
// k0 part: 32-row slab per block. Phase 1: 8 f32x4 loads, ALL issued (sched_barrier pin);
// phase 2: plain outq stores + one 16B Qbf store per 32B chunk. Qbf tile at byte
// tile_idx*32768; 16B chunk (rr,c16) at rr*512 + ((c16^(rr&31))<<4) — the LDS image k2
// reads. PhiF 16B-chunk idx for (row r, k-chunk c): ((r>>4)*8+(c>>2))*64+(c&3)*16+(r&15).
__global__ __launch_bounds__(256)
void k01_prep(const float* __restrict__ queue, float* __restrict__ outq,
              char* __restrict__ Qbf,
              const float* __restrict__ p1, const float* __restrict__ p2,
              float* __restrict__ Pn, float* __restrict__ PnT,
              unsigned short* __restrict__ PhiF,
              unsigned int* __restrict__ rowmaxU, unsigned long long* __restrict__ rowfinal)
{
    const int bid = blockIdx.x;
    const int t = threadIdx.x;       // 0..255

    if (bid >= 256) {
        // ---------- k0: FIFO copy + Qbf ----------
        const int b0 = bid - 256;               // 0..2047
        const int n0 = b0 * 32;
        const f32x4* qsrc = (const f32x4*)(queue + (size_t)n0 * DIM);
        f32x4* qdst = (f32x4*)(outq + (size_t)(n0 + BATCH) * DIM);
        char* tile = Qbf + (size_t)(b0 >> 1) * 32768;

        f32x4 va[8];
        #pragma unroll
        for (int it = 0; it < 4; ++it) {
            const int L = it * 256 + t;          // 0..1023: 32B chunk id
            const int r = L >> 5, c16 = L & 31;
            va[2 * it]     = qsrc[(size_t)r * 64 + c16 * 2];
            va[2 * it + 1] = qsrc[(size_t)r * 64 + c16 * 2 + 1];
        }
        __builtin_amdgcn_sched_barrier(0);       // pin: all 8 loads issued before stores
        #pragma unroll
        for (int it = 0; it < 4; ++it) {
            const int L = it * 256 + t;
            const int r = L >> 5, c16 = L & 31;
            f32x4 v0 = va[2 * it], v1 = va[2 * it + 1];
            if (n0 + r < QUEUE - BATCH) {
                qdst[(size_t)r * 64 + c16 * 2]     = v0;
                qdst[(size_t)r * 64 + c16 * 2 + 1] = v1;
            }
            bf16x8 bb;
            bb[0] = (short)f2bf(v0.x); bb[1] = (short)f2bf(v0.y);
            bb[2] = (short)f2bf(v0.z); bb[3] = (short)f2bf(v0.w);
            bb[4] = (short)f2bf(v1.x); bb[5] = (short)f2bf(v1.y);
            bb[6] = (short)f2bf(v1.z); bb[7] = (short)f2bf(v1.w);
            const int rr = ((b0 & 1) << 5) + r;   // row within 64-row tile
            *(bf16x8*)(tile + rr * 512 + ((c16 ^ (rr & 31)) << 4)) = bb;
        }
    } else {
        // ---------- k1: normalize 4 rows (one per wave) ----------
        const int sub = t >> 6, lane = t & 63;
        const int r = bid * 4 + sub;             // 0..1023
        if (lane == 0) {                          // ws re-poisoned 0xAA each call
            rowmaxU[r] = 0u;
            rowfinal[r] = 0ull;
        }
        const float* src = (r < BATCH) ? p1 : p2;
        const int row = (r < BATCH) ? r : r - BATCH;
        float4 v = ((const float4*)(src + (size_t)row * DIM))[lane];
        float sq = v.x*v.x + v.y*v.y + v.z*v.z + v.w*v.w;
        #pragma unroll
        for (int off = 32; off; off >>= 1) sq += __shfl_xor(sq, off, 64);
        sq = fmaxf(sq, 1e-12f);
        float s = rsqrtf(sq);
        s = s * (1.5f - 0.5f * sq * s * s);
        v.x *= s; v.y *= s; v.z *= s; v.w *= s;
        ((float4*)(Pn + (size_t)r * DIM))[lane] = v;
        const int k = lane * 4;
        PnT[(size_t)(k + 0) * MROWS + r] = v.x;
        PnT[(size_t)(k + 1) * MROWS + r] = v.y;
        PnT[(size_t)(k + 2) * MROWS + r] = v.z;
        PnT[(size_t)(k + 3) * MROWS + r] = v.w;
        short4 b;
        b.x = (short)f2bf(v.x); b.y = (short)f2bf(v.y);
        b.z = (short)f2bf(v.z); b.w = (short)f2bf(v.w);
        {
            const int c = lane >> 1;
            const int idx = ((r >> 4) * 8 + (c >> 2)) * 64 + (c & 3) * 16 + (r & 15);
            *(short4*)((char*)PhiF + (size_t)idx * 16 + (lane & 1) * 8) = b;
        }
        if (r < BATCH) ((float4*)(outq + (size_t)r * DIM))[lane] = v;  // new_queue[0:512] = p1n
    }
}

// ---------------- k2: bf16 MFMA GEMM filter, depth-2 counted-vmcnt pipeline ----------------
// Grid 1024; bid remap c=(bid>>5)*8+(bid&7), s=(bid>>3)&3 (XCD sharing of Qbf chunks).
// Block = 256 thr = 4 waves; wave w: m-rows [s*256 + w*64, +64), pfr[4][8] resident.
// 8 half-tiles of 32 rows (16KB) per chunk, 4 LDS buffers. Per half h:
//   issue stage(h+2) -> s_waitcnt vmcnt(N) [FIFO-exact] -> s_barrier -> 16 ds_read +
//   64 MFMA + epilogue (4 cand stores) -> s_barrier.
// vmcnt N: h=0:8 [s1,s2]; h=1..5:12 [stores(h-1),s(h+1),s(h+2)]; h=6:8; h=7:4.
__device__ __forceinline__ void k2_stage_half(const char* __restrict__ src,
                                              char* dst, int t)
{
    #pragma unroll
    for (int it = 0; it < 4; ++it) {
        const int L = it * 256 + t;          // 0..1023 chunks of 16B
        __builtin_amdgcn_global_load_lds(
            (const __attribute__((address_space(1))) unsigned int*)(src + (size_t)L * 16),
            (__attribute__((address_space(3))) unsigned int*)(dst + L * 16), 16, 0, 0);
    }
}

__global__ __launch_bounds__(256, 2)
void k2_mfma(const unsigned short* __restrict__ PhiF, const char* __restrict__ Qbf,
             float* __restrict__ cand, unsigned int* __restrict__ rowmaxU)
{
    __shared__ __align__(16) char Bs[4][16384];
    const int bid = blockIdx.x;      // 0..1023
    const int c = (bid >> 5) * 8 + (bid & 7);   // n-chunk 0..255
    const int s = (bid >> 3) & 3;               // m-strip 0..3
    const int t  = threadIdx.x;
    const int w  = t >> 6, lane = t & 63;
    const int lr = lane & 15, q = lane >> 4;
    const int mbase = s * 256 + w * 64;
    const char* chunkbase = Qbf + (size_t)(c * 4) * 32768;   // 8 halves x 16KB

    // ---- preload P fragments: 64 m-rows x K=256 resident; coalesced from PhiF
    bf16x8 pfr[4][8];
    {
        const char* Pw = (const char*)PhiF;
        const int mt16b = mbase >> 4;        // base 16-row tile index
        #pragma unroll
        for (int mj = 0; mj < 4; ++mj)
            #pragma unroll
            for (int ks = 0; ks < 8; ++ks)
                pfr[mj][ks] = *(const bf16x8*)(Pw + ((size_t)((mt16b + mj) * 8 + ks) * 64 + lane) * 16);
    }

    k2_stage_half(chunkbase,         Bs[0], t);
    k2_stage_half(chunkbase + 16384, Bs[1], t);

    float rowmx[4] = {-1e30f, -1e30f, -1e30f, -1e30f};

    #pragma unroll
    for (int h = 0; h < 8; ++h) {
        if (h + 2 < 8)
            k2_stage_half(chunkbase + (size_t)(h + 2) * 16384, Bs[(h + 2) & 3], t);

        // FIFO-exact wait: everything up through stage(h) drained.
        if (h == 0)      asm volatile("s_waitcnt vmcnt(8)"  ::: "memory");
        else if (h <= 5) asm volatile("s_waitcnt vmcnt(12)" ::: "memory");
        else if (h == 6) asm volatile("s_waitcnt vmcnt(8)"  ::: "memory");
        else             asm volatile("s_waitcnt vmcnt(4)"  ::: "memory");
        __builtin_amdgcn_s_barrier();
        __builtin_amdgcn_sched_barrier(0);

        const char* Bsb = Bs[h & 3];
        f32x4 acc[2][4];                 // [ni][mj]
        #pragma unroll
        for (int i = 0; i < 2; ++i)
            #pragma unroll
            for (int j = 0; j < 4; ++j) acc[i][j] = (f32x4){0.f, 0.f, 0.f, 0.f};

        #pragma unroll
        for (int ks = 0; ks < 8; ++ks) {
            bf16x8 qf[2];
            #pragma unroll
            for (int ni = 0; ni < 2; ++ni) {
                const int rl = ni * 16 + lr;            // local row 0..31
                const int c16 = ks * 4 + q;
                qf[ni] = *(const bf16x8*)(Bsb + rl * 512 + ((c16 ^ rl) << 4));
            }
            #pragma unroll
            for (int ni = 0; ni < 2; ++ni)
                #pragma unroll
                for (int mj = 0; mj < 4; ++mj)
                    acc[ni][mj] = __builtin_amdgcn_mfma_f32_16x16x32_bf16(qf[ni], pfr[mj][ks], acc[ni][mj], 0, 0, 0);
        }

        // ---- epilogue: per (m, 32-n-group) max; group = c*8 + h.
        #pragma unroll
        for (int mj = 0; mj < 4; ++mj) {
            f32x4 va = acc[0][mj], vb = acc[1][mj];
            float mx = fmaxf(fmaxf(fmaxf(va[0], va[1]), fmaxf(va[2], va[3])),
                             fmaxf(fmaxf(vb[0], vb[1]), fmaxf(vb[2], vb[3])));
            mx = fmaxf(mx, __shfl_xor(mx, 16, 64));
            mx = fmaxf(mx, __shfl_xor(mx, 32, 64));
            rowmx[mj] = fmaxf(rowmx[mj], mx);
            if (q == 0)
                cand[(size_t)(c * 8 + h) * MROWS + (mbase + mj * 16 + lr)] = mx;
        }
        __builtin_amdgcn_s_barrier();
        __builtin_amdgcn_sched_barrier(0);
    }

    // ---- fused rowmax: one atomic per m per block
    if (q == 0) {
        #pragma unroll
        for (int mj = 0; mj < 4; ++mj)
            atomicMax(rowmaxU + mbase + mj * 16 + lr, mono_f32(rowmx[mj]));
    }
}

// ---------------- k2cd: margin filter -> LDS hit list -> exact fp32 rescore ----------------
// Grid 512 = 16 m-chunks x 32 g-chunks (64 g each). Phase 1: scan cand, push hits to LDS
// (cap 4096 = 64m x 64g max). Phase 2: waves rescore hits round-robin; one wave per
// (row,group): 32 cols x 256-dim fp32 dot, atomicMax(rowfinal).
__global__ __launch_bounds__(256)
void k2cd(const float* __restrict__ cand, const unsigned int* __restrict__ rowmaxU,
          const float* __restrict__ Pn, const float* __restrict__ queue,
          unsigned long long* __restrict__ rowfinal)
{
    __shared__ unsigned int hits[4096];
    __shared__ int nhits;
    const int t = threadIdx.x;               // 256
    if (t == 0) nhits = 0;
    __syncthreads();

    {   // ---- phase 1: filter
        const int ml = t & 63, gs = t >> 6;
        const int mc = blockIdx.x & 15, gc = blockIdx.x >> 4;   // gc 0..31
        const int m  = mc * 64 + ml;
        const int g0 = gc * 64 + gs * 16;
        const float thr = unmono_f32(rowmaxU[m]) - MARGIN;
        #pragma unroll 8
        for (int j = 0; j < 16; ++j) {
            if (cand[(size_t)(g0 + j) * MROWS + m] >= thr) {
                int p = atomicAdd(&nhits, 1);
                hits[p] = ((unsigned int)m << 16) | (unsigned int)(g0 + j);
            }
        }
    }
    __syncthreads();

    // ---- phase 2: rescore
    const int n = nhits;
    const int w = t >> 6, lane = t & 63;
    const int col_l = lane & 31, half = lane >> 5;
    for (int p = w; p < n; p += 4) {
        const unsigned int pr = hits[p];
        const int row = pr >> 16, g = pr & 0xffff;
        const int col = g * 32 + col_l;
        const float4* qp = (const float4*)(queue + (size_t)col * DIM + half * 128);
        const float4* pp = (const float4*)(Pn + (size_t)row * DIM + half * 128);
        float4 sv = {0.f, 0.f, 0.f, 0.f};
        #pragma unroll 8
        for (int j = 0; j < 32; ++j) {
            float4 a = pp[j], b = qp[j];
            sv.x = fmaf(a.x, b.x, sv.x); sv.y = fmaf(a.y, b.y, sv.y);
            sv.z = fmaf(a.z, b.z, sv.z); sv.w = fmaf(a.w, b.w, sv.w);
        }
        float s = (sv.x + sv.y) + (sv.z + sv.w);
        s += __shfl_xor(s, 32, 64);                       // combine k-halves
        unsigned long long best = ((unsigned long long)mono_f32(s) << 32)
                                | (unsigned int)(65535 - col);
        #pragma unroll
        for (int off = 1; off <= 16; off <<= 1) {
            unsigned long long o = __shfl_xor(best, off, 64);
            best = best > o ? best : o;
        }
        if (lane == 0) atomicMax(rowfinal + row, best);
    }
}

// ---------------- k3: S1/S2 similarity matrices (4 rows x 256-col half per block) --------
// grid 512: b>>1 = 4-row block (rows of [nn1;nn2]), b&1 = column half.
__global__ void k3_sim(const unsigned long long* __restrict__ rowfinal,
                       const float* __restrict__ queue,
                       const float* __restrict__ PnT, float* __restrict__ S)
{
    const int b  = blockIdx.x;       // 0..511
    const int rb = (b >> 1) * 4;     // 0..1020 (rows of [nn1;nn2])
    const int ch = b & 1;            // column half
    const int tid = threadIdx.x;     // 256
    const int which = (rb < BATCH) ? 0 : 1;
    const int colbase = which ? 0 : BATCH;    // S1 vs p2 (cols 512..1023), S2 vs p1 (0..511)
    const int col = colbase + ch * 256 + tid;
    __shared__ float nnv[4][DIM];
    #pragma unroll
    for (int j = 0; j < 4; ++j) {
        const int idx = 65535 - (int)(rowfinal[rb + j] & 0xFFFFull);
        nnv[j][tid] = queue[(size_t)idx * DIM + tid];
    }
    __syncthreads();
    float acc[4];
    #pragma unroll
    for (int j = 0; j < 4; ++j) acc[j] = 0.f;
    for (int k4 = 0; k4 < 64; ++k4) {
        float4 nv[4];
        #pragma unroll
        for (int j = 0; j < 4; ++j) nv[j] = ((const float4*)nnv[j])[k4];
        #pragma unroll
        for (int kk = 0; kk < 4; ++kk) {
            const int k = k4 * 4 + kk;
            const float v0 = PnT[(size_t)k * MROWS + col];
            #pragma unroll
            for (int j = 0; j < 4; ++j) {
                const float nj = ((const float*)&nv[j])[kk];
                acc[j] = fmaf(nj, v0, acc[j]);
            }
        }
    }
    const int i0 = rb & (BATCH - 1);
    float* Sout = S + (size_t)which * (BATCH * BATCH);
    #pragma unroll
    for (int j = 0; j < 4; ++j)
        Sout[(size_t)(i0 + j) * BATCH + ch * 256 + tid] = acc[j] * 10.0f;
}

// ---------------- k4: loss ----------------
__global__ void k4_loss(const float* __restrict__ S, float* __restrict__ loss)
{
    const int r = blockIdx.x;        // 0..2047
    const int tid = threadIdx.x;     // 256
    const int grp = r >> 9;
    const int i = r & 511;
    const float* M = S + (size_t)(grp >> 1) * (BATCH * BATCH);
    float x0, x1;
    if (!(grp & 1)) { x0 = M[(size_t)i * BATCH + tid];  x1 = M[(size_t)i * BATCH + tid + 256]; }
    else            { x0 = M[(size_t)tid * BATCH + i];  x1 = M[(size_t)(tid + 256) * BATCH + i]; }
    const float diag = M[(size_t)i * BATCH + i];
    float mx = fmaxf(x0, x1);
    #pragma unroll
    for (int off = 1; off < 64; off <<= 1) mx = fmaxf(mx, __shfl_xor(mx, off, 64));
    __shared__ float redm[4], reds[4];
    if ((tid & 63) == 0) redm[tid >> 6] = mx;
    __syncthreads();
    mx = fmaxf(fmaxf(redm[0], redm[1]), fmaxf(redm[2], redm[3]));
    float e = __expf(x0 - mx) + __expf(x1 - mx);
    #pragma unroll
    for (int off = 1; off < 64; off <<= 1) e += __shfl_xor(e, off, 64);
    if ((tid & 63) == 0) reds[tid >> 6] = e;
    __syncthreads();
    if (tid == 0)
        loss[r] = mx + logf(reds[0] + reds[1] + reds[2] + reds[3]) - diag;
}

// ---------------- launcher ----------------
extern "C" void kernel_launch(void* const* d_in, const int* in_sizes, int n_in,
                              void* d_out, int out_size, void* d_ws, size_t ws_size,
                              hipStream_t stream)
{
    const float* p1    = (const float*)d_in[0];
    const float* p2    = (const float*)d_in[1];
    const float* queue = (const float*)d_in[2];
    float* out  = (float*)d_out;
    float* loss = out;
    float* outq = out + 4 * BATCH;

    // Workspace (~44.5 MB)
    char* w = (char*)d_ws;
    float* cand = (float*)w;                               w += (size_t)NGRP * MROWS * 4;   // 8 MB [g][m]
    unsigned long long* rowfinal = (unsigned long long*)w; w += MROWS * 8;
    unsigned int* rowmaxU = (unsigned int*)w;              w += MROWS * 4;
    float* Pn  = (float*)w;                                w += (size_t)MROWS * DIM * 4;    // 1 MB
    float* PnT = (float*)w;                                w += (size_t)MROWS * DIM * 4;    // 1 MB
    unsigned short* PhiF = (unsigned short*)w;             w += (size_t)MROWS * DIM * 2;    // 0.5 MB
    float* S = (float*)w;                                  w += (size_t)2 * BATCH * BATCH * 4; // 2 MB
    char* Qbf = w;                                         // 32 MB (QUEUE*DIM*2)

    hipLaunchKernelGGL(k01_prep,    dim3(256 + 2048), dim3(256), 0, stream,
                       queue, outq, Qbf, p1, p2, Pn, PnT, PhiF, rowmaxU, rowfinal);
    hipLaunchKernelGGL(k2_mfma,     dim3(1024), dim3(256), 0, stream, PhiF, Qbf, cand, rowmaxU);
    hipLaunchKernelGGL(k2cd,        dim3(512),  dim3(256), 0, stream, cand, rowmaxU, Pn, queue, rowfinal);
    hipLaunchKernelGGL(k3_sim,      dim3(512),  dim3(256), 0, stream, rowfinal, queue, PnT, S);
    hipLaunchKernelGGL(k4_loss,     dim3(4 * BATCH), dim3(256), 0, stream, S, loss);
}